// Round 1
// baseline (6245.079 us; speedup 1.0000x reference)
//
#include <hip/hip_runtime.h>
#include <math.h>

#define BB   512
#define TT   243
#define DIMV 512
#define CC   256   // channels per branch
#define CHH  128   // hidden channels in ECL
#define FF   122   // (T+1)/2 output freqs
#define NKK  122   // T/2+1 rfft bins
#define TS   9     // t-rows per block in res GEMM (243 = 27*9)

// ---------------- GlobalFilter: build M = irfft( lf @ rfft ) ----------------

__global__ void k_compute_A(const float* __restrict__ lf, float* __restrict__ A) {
  int idx = blockIdx.x * 256 + threadIdx.x;
  if (idx >= FF * TT) return;
  int f = idx / TT, tp = idx - f * TT;
  float are = 0.f, aim = 0.f;
  for (int k = 0; k < NKK; ++k) {
    int m = (k * tp) % TT;                       // exact int phase reduction
    float ph = -6.28318530717958647692f * (float)m / (float)TT;
    float s, c;
    sincosf(ph, &s, &c);
    float lr = lf[(f * NKK + k) * 2 + 0];
    float li = lf[(f * NKK + k) * 2 + 1];
    are = fmaf(lr, c, fmaf(-li, s, are));        // Re(lf * e^{i ph})
    aim = fmaf(lr, s, fmaf(li, c, aim));         // Im(lf * e^{i ph})
  }
  A[idx * 2 + 0] = are;
  A[idx * 2 + 1] = aim;
}

__global__ void k_compute_M(const float* __restrict__ A, float* __restrict__ M) {
  int idx = blockIdx.x * 256 + threadIdx.x;
  if (idx >= TT * TT) return;
  int t = idx / TT, tp = idx - t * TT;
  float acc = A[tp * 2 + 0];                     // f = 0 term: Re A[0,tp] (Im Y0 ignored by irfft)
  for (int f = 1; f < FF; ++f) {
    int m = (f * t) % TT;
    float ph = 6.28318530717958647692f * (float)m / (float)TT;
    float s, c;
    sincosf(ph, &s, &c);
    float ar = A[(f * TT + tp) * 2 + 0];
    float ai = A[(f * TT + tp) * 2 + 1];
    acc = fmaf(2.f * ar, c, fmaf(-2.f * ai, s, acc));
  }
  M[idx] = acc * (1.0f / (float)TT);
}

// ---------------- res branch: out[b,t,c] = sum_tp M[t,tp] * x[b,tp,c], c<256 ----------------

__global__ void k_res(const float* __restrict__ x, const float* __restrict__ M,
                      float* __restrict__ out) {
  int blk = blockIdx.x;                          // b * 27 + tchunk
  int b = blk / (TT / TS);
  int t0 = (blk - b * (TT / TS)) * TS;
  int c = threadIdx.x;                           // 0..255
  const float* xb = x + (size_t)b * TT * DIMV + c;
  float acc[TS];
#pragma unroll
  for (int j = 0; j < TS; ++j) acc[j] = 0.f;
  for (int tp = 0; tp < TT; ++tp) {
    float xv = xb[(size_t)tp * DIMV];
#pragma unroll
    for (int j = 0; j < TS; ++j)
      acc[j] = fmaf(M[(t0 + j) * TT + tp], xv, acc[j]);
  }
  float* ob = out + ((size_t)b * TT + t0) * DIMV + c;
#pragma unroll
  for (int j = 0; j < TS; ++j) ob[(size_t)j * DIMV] = acc[j];
}

// ---------------- gate branch: conv1 (groups=2,k=3) + LN + gelu ----------------

__global__ void k_conv1(const float* __restrict__ x, const float* __restrict__ w1,
                        const float* __restrict__ g1, const float* __restrict__ b1,
                        float* __restrict__ h1) {
  __shared__ float xs[3][CC];
  __shared__ float red[2][2];
  int bt = blockIdx.x;
  int b = bt / TT, t = bt - b * TT;
  int o = threadIdx.x;                           // 0..127 output channel
  const float* xb = x + (size_t)b * TT * DIMV;
  for (int i = o; i < 3 * CC; i += CHH) {
    int dt = i >> 8;                             // row 0..2
    int ch = i & 255;
    int tt = t + dt - 1;
    xs[dt][ch] = (tt >= 0 && tt < TT) ? xb[(size_t)tt * DIMV + CC + ch] : 0.f;
  }
  __syncthreads();
  int g = o >> 6;                                // feature_group_count=2: out 0..63 <- in 0..127, 64..127 <- in 128..255
  const float* wrow = w1 + o * (CHH * 3);        // w1[o, i, k], [128,128,3]
  const float* x0 = &xs[0][g * 128];
  const float* x1 = &xs[1][g * 128];
  const float* x2 = &xs[2][g * 128];
  float acc = 0.f;
#pragma unroll 4
  for (int i = 0; i < 128; ++i) {
    acc = fmaf(wrow[i * 3 + 0], x0[i], acc);
    acc = fmaf(wrow[i * 3 + 1], x1[i], acc);
    acc = fmaf(wrow[i * 3 + 2], x2[i], acc);
  }
  // LayerNorm over the 128 outputs (2 waves)
  float s = acc, s2 = acc * acc;
#pragma unroll
  for (int off = 32; off > 0; off >>= 1) {
    s += __shfl_down(s, off);
    s2 += __shfl_down(s2, off);
  }
  int wave = o >> 6, lane = o & 63;
  if (lane == 0) { red[0][wave] = s; red[1][wave] = s2; }
  __syncthreads();
  float mean = (red[0][0] + red[0][1]) * (1.f / 128.f);
  float var  = (red[1][0] + red[1][1]) * (1.f / 128.f) - mean * mean;
  float xn = (acc - mean) * rsqrtf(var + 1e-5f) * g1[o] + b1[o];
  float ge = 0.5f * xn * (1.f + erff(xn * 0.70710678118654752f));  // exact gelu
  h1[(size_t)bt * CHH + o] = ge;
}

// ---------------- gate branch: conv2 (groups=2,k=3) + LN + sigmoid + multiply ----------------

__global__ void k_conv2(const float* __restrict__ x, const float* __restrict__ hsrc,
                        const float* __restrict__ w2,
                        const float* __restrict__ g2, const float* __restrict__ b2,
                        float* __restrict__ out) {
  __shared__ float hs[3][CHH];
  __shared__ float red[2][4];
  int bt = blockIdx.x;
  int b = bt / TT, t = bt - b * TT;
  int o = threadIdx.x;                           // 0..255 output channel
  const float* hb = hsrc + (size_t)b * TT * CHH;
  for (int i = o; i < 3 * CHH; i += 256) {
    int dt = i / CHH;
    int ch = i - dt * CHH;
    int tt = t + dt - 1;
    hs[dt][ch] = (tt >= 0 && tt < TT) ? hb[(size_t)tt * CHH + ch] : 0.f;
  }
  __syncthreads();
  int g = o >> 7;                                // out 0..127 <- h 0..63 ; out 128..255 <- h 64..127
  const float* wrow = w2 + o * (64 * 3);         // w2[o, i, k], [256,64,3]
  const float* h0 = &hs[0][g * 64];
  const float* h1r = &hs[1][g * 64];
  const float* h2 = &hs[2][g * 64];
  float acc = 0.f;
#pragma unroll 4
  for (int i = 0; i < 64; ++i) {
    acc = fmaf(wrow[i * 3 + 0], h0[i], acc);
    acc = fmaf(wrow[i * 3 + 1], h1r[i], acc);
    acc = fmaf(wrow[i * 3 + 2], h2[i], acc);
  }
  // LayerNorm over 256 outputs (4 waves)
  float s = acc, s2 = acc * acc;
#pragma unroll
  for (int off = 32; off > 0; off >>= 1) {
    s += __shfl_down(s, off);
    s2 += __shfl_down(s2, off);
  }
  int wave = o >> 6, lane = o & 63;
  if (lane == 0) { red[0][wave] = s; red[1][wave] = s2; }
  __syncthreads();
  float sum  = red[0][0] + red[0][1] + red[0][2] + red[0][3];
  float sum2 = red[1][0] + red[1][1] + red[1][2] + red[1][3];
  float mean = sum * (1.f / 256.f);
  float var  = sum2 * (1.f / 256.f) - mean * mean;
  float xn = (acc - mean) * rsqrtf(var + 1e-5f) * g2[o] + b2[o];
  float sg = 1.f / (1.f + expf(-xn));
  size_t base = ((size_t)b * TT + t) * DIMV + CC + o;
  out[base] = x[base] * sg;                      // gate * sigmoid(LN(conv2))
}

// ---------------- launch ----------------

extern "C" void kernel_launch(void* const* d_in, const int* in_sizes, int n_in,
                              void* d_out, int out_size, void* d_ws, size_t ws_size,
                              hipStream_t stream) {
  const float* x  = (const float*)d_in[0];
  const float* lf = (const float*)d_in[1];
  const float* w1 = (const float*)d_in[2];
  const float* w2 = (const float*)d_in[3];
  const float* g1 = (const float*)d_in[4];
  const float* b1 = (const float*)d_in[5];
  const float* g2 = (const float*)d_in[6];
  const float* b2 = (const float*)d_in[7];
  float* out = (float*)d_out;

  char* ws = (char*)d_ws;
  float* A  = (float*)(ws);                 // 122*243*2 floats = 237168 B
  float* M  = (float*)(ws + 262144);        // 243*243 floats   = 236196 B
  float* h1 = (float*)(ws + 524288);        // 512*243*128 floats = 63.7 MB

  k_compute_A<<<(FF * TT + 255) / 256, 256, 0, stream>>>(lf, A);
  k_compute_M<<<(TT * TT + 255) / 256, 256, 0, stream>>>(A, M);
  k_res<<<BB * (TT / TS), 256, 0, stream>>>(x, M, out);
  k_conv1<<<BB * TT, CHH, 0, stream>>>(x, w1, g1, b1, h1);
  k_conv2<<<BB * TT, 256, 0, stream>>>(x, h1, w2, g2, b2, out);
}

// Round 2
// 1155.286 us; speedup vs baseline: 5.4057x; 5.4057x over previous
//
#include <hip/hip_runtime.h>
#include <math.h>

typedef unsigned short ushort_t;

#define BB   512
#define TT   243
#define DIMV 512
#define CC   256   // channels per branch
#define CHH  128   // hidden channels
#define FF   122   // (T+1)/2 output freqs
#define NKK  122   // T/2+1 rfft bins

__device__ __forceinline__ float b2f(ushort_t u) {
  union { unsigned int i; float f; } z; z.i = ((unsigned int)u) << 16; return z.f;
}
__device__ __forceinline__ ushort_t f2b(float f) {
  union { float f; unsigned int i; } z; z.f = f;
  unsigned int r = (z.i + 0x7fffu + ((z.i >> 16) & 1u)) >> 16;
  return (ushort_t)r;
}

// ---------------- GlobalFilter: build Mt[tp][t] = irfft( lf @ rfft ) ----------------

__global__ void k_compute_A(const float* __restrict__ lf, float* __restrict__ A) {
  int idx = blockIdx.x * 256 + threadIdx.x;
  if (idx >= FF * TT) return;
  int f = idx / TT, tp = idx - f * TT;
  float are = 0.f, aim = 0.f;
  for (int k = 0; k < NKK; ++k) {
    int m = (k * tp) % TT;
    float ph = -6.28318530717958647692f * (float)m / (float)TT;
    float s, c;
    sincosf(ph, &s, &c);
    float lr = lf[(f * NKK + k) * 2 + 0];
    float li = lf[(f * NKK + k) * 2 + 1];
    are = fmaf(lr, c, fmaf(-li, s, are));
    aim = fmaf(lr, s, fmaf(li, c, aim));
  }
  A[idx * 2 + 0] = are;
  A[idx * 2 + 1] = aim;
}

__global__ void k_compute_M(const float* __restrict__ A, float* __restrict__ Mt) {
  int idx = blockIdx.x * 256 + threadIdx.x;
  if (idx >= TT * TT) return;
  int t = idx / TT, tp = idx - t * TT;
  float acc = A[tp * 2 + 0];
  for (int f = 1; f < FF; ++f) {
    int m = (f * t) % TT;
    float ph = 6.28318530717958647692f * (float)m / (float)TT;
    float s, c;
    sincosf(ph, &s, &c);
    float ar = A[(f * TT + tp) * 2 + 0];
    float ai = A[(f * TT + tp) * 2 + 1];
    acc = fmaf(2.f * ar, c, fmaf(-2.f * ai, s, acc));
  }
  Mt[tp * TT + t] = acc * (1.0f / (float)TT);   // transposed: row tp contiguous in t
}

// ---------------- res: out[b,t,c] = sum_tp Mt[tp][t] * x[b,tp,c], c<256 ----------------
// TS=81: x re-read 3x instead of 27x; Mt row chunk is 81 contiguous uniform floats -> s_loads.

#define TS 81
__global__ void k_res(const float* __restrict__ x, const float* __restrict__ Mt,
                      float* __restrict__ out) {
  int blk = blockIdx.x;
  int b = blk / 3, tc = blk - b * 3;
  int t0 = tc * TS;
  int c = threadIdx.x;
  const float* xb = x + (size_t)b * TT * DIMV + c;
  float acc[TS];
#pragma unroll
  for (int j = 0; j < TS; ++j) acc[j] = 0.f;
  for (int tp = 0; tp < TT; ++tp) {
    float xv = xb[(size_t)tp * DIMV];
    const float* m = Mt + tp * TT + t0;          // block-uniform address
#pragma unroll
    for (int j = 0; j < TS; ++j) acc[j] = fmaf(m[j], xv, acc[j]);
  }
  float* ob = out + ((size_t)b * TT + t0) * DIMV + c;
#pragma unroll
  for (int j = 0; j < TS; ++j) ob[(size_t)j * DIMV] = acc[j];
}

// ---------------- conv1 + LN + gelu  (lane = t, wave-uniform weights) ----------------
// x gate half [B,T,256] -> h1t [B,128,T] bf16 (transposed for coalescing)

#define XST 258   // bf16 elements per staged row (256 + pad2) -> lane bank stride 129 dwords = free
#define HST 66

__global__ __launch_bounds__(256) void k_conv1(const float* __restrict__ x,
    const float* __restrict__ w1, const float* __restrict__ g1, const float* __restrict__ b1,
    ushort_t* __restrict__ h1t) {
  __shared__ ushort_t xs[66 * XST];
  __shared__ ushort_t ht[128 * HST];
  __shared__ float red[2][4][64];
  int b = blockIdx.x >> 2, tile = blockIdx.x & 3;
  int t0 = tile * 64;
  int tw = TT - t0; if (tw > 64) tw = 64;
  int tid = threadIdx.x, lane = tid & 63, wave = tid >> 6;

  const float* xb = x + (size_t)b * TT * DIMV + CC;
  for (int e = tid; e < 66 * 256; e += 256) {
    int r = e >> 8, ch = e & 255;
    int t = t0 - 1 + r;
    float v = (t >= 0 && t < TT) ? xb[(size_t)t * DIMV + ch] : 0.f;
    xs[r * XST + ch] = f2b(v);
  }
  __syncthreads();

  int o0w = wave * 32;                 // this wave's 32 output channels
  int gi = (o0w >= 64) ? 128 : 0;      // group: out 0..63 <- in 0..127, 64..127 <- in 128..255
  const ushort_t* xrow0 = xs + (lane + 0) * XST + gi;
  const ushort_t* xrow1 = xs + (lane + 1) * XST + gi;
  const ushort_t* xrow2 = xs + (lane + 2) * XST + gi;
  float s = 0.f, s2 = 0.f;

  for (int cch = 0; cch < 2; ++cch) {
    int o0 = o0w + cch * 16;
    int o0u = __builtin_amdgcn_readfirstlane(o0);
    const float* wp = w1 + (size_t)o0u * 384;    // wave-uniform -> scalar loads
    float acc[16];
#pragma unroll
    for (int oo = 0; oo < 16; ++oo) acc[oo] = 0.f;
#pragma unroll 2
    for (int i = 0; i < 128; ++i) {
      float x0 = b2f(xrow0[i]), x1 = b2f(xrow1[i]), x2 = b2f(xrow2[i]);
      const float* w = wp + i * 3;
#pragma unroll
      for (int oo = 0; oo < 16; ++oo) {
        float a = acc[oo];
        a = fmaf(w[oo * 384 + 0], x0, a);
        a = fmaf(w[oo * 384 + 1], x1, a);
        a = fmaf(w[oo * 384 + 2], x2, a);
        acc[oo] = a;
      }
    }
#pragma unroll
    for (int oo = 0; oo < 16; ++oo) {
      float v = acc[oo];
      s += v; s2 += v * v;
      ht[(o0 + oo) * HST + lane] = f2b(v);
    }
  }
  red[0][wave][lane] = s;
  red[1][wave][lane] = s2;
  __syncthreads();

  // LN stats at t = lane (over 128 channels)
  float sum  = red[0][0][lane] + red[0][1][lane] + red[0][2][lane] + red[0][3][lane];
  float sum2 = red[1][0][lane] + red[1][1][lane] + red[1][2][lane] + red[1][3][lane];
  float mean = sum * (1.f / 128.f);
  float var  = sum2 * (1.f / 128.f) - mean * mean;
  float rstd = rsqrtf(var + 1e-5f);

  ushort_t* hb = h1t + (size_t)b * CHH * TT + t0;
  for (int it = 0; it < 32; ++it) {
    int o = 4 * it + wave;                       // wave-uniform per instruction
    float v = b2f(ht[o * HST + lane]);
    float xn = (v - mean) * rstd * g1[o] + b1[o];
    float ge = 0.5f * xn * (1.f + erff(xn * 0.70710678118654752f));
    if (lane < tw) hb[(size_t)o * TT + lane] = f2b(ge);
  }
}

// ---------------- conv2 + LN + sigmoid + gate-mul  (lane = t) ----------------
// h1t [B,128,T] bf16 -> out[b,t,256+o] = x_gate * sigmoid(LN(conv2))

#define HST2 130  // bf16 row stride (128 + pad2): lane bank stride 65 dwords -> free
#define OST  66

__global__ __launch_bounds__(256) void k_conv2(const float* __restrict__ x,
    const ushort_t* __restrict__ h1t, const float* __restrict__ w2,
    const float* __restrict__ g2, const float* __restrict__ b2,
    float* __restrict__ out) {
  __shared__ ushort_t hs[66 * HST2];
  __shared__ ushort_t ot[256 * OST];
  __shared__ float red[2][4][64];
  int b = blockIdx.x >> 2, tile = blockIdx.x & 3;
  int t0 = tile * 64;
  int tw = TT - t0; if (tw > 64) tw = 64;
  int tid = threadIdx.x, lane = tid & 63, wave = tid >> 6;

  const ushort_t* hbase = h1t + (size_t)b * CHH * TT;
  for (int e = tid; e < 128 * 66; e += 256) {
    int i = e / 66, r = e - i * 66;
    int t = t0 - 1 + r;
    hs[r * HST2 + i] = (t >= 0 && t < TT) ? hbase[(size_t)i * TT + t] : (ushort_t)0;
  }
  __syncthreads();

  int o0w = wave * 64;                 // this wave's 64 output channels
  int gi = (o0w >= 128) ? 64 : 0;      // group: out 0..127 <- h 0..63, 128..255 <- h 64..127
  const ushort_t* h0 = hs + (lane + 0) * HST2 + gi;
  const ushort_t* h1r = hs + (lane + 1) * HST2 + gi;
  const ushort_t* h2 = hs + (lane + 2) * HST2 + gi;
  float s = 0.f, s2 = 0.f;

  for (int cch = 0; cch < 4; ++cch) {
    int o0 = o0w + cch * 16;
    int o0u = __builtin_amdgcn_readfirstlane(o0);
    const float* wp = w2 + (size_t)o0u * 192;    // wave-uniform -> scalar loads
    float acc[16];
#pragma unroll
    for (int oo = 0; oo < 16; ++oo) acc[oo] = 0.f;
#pragma unroll 2
    for (int i = 0; i < 64; ++i) {
      float v0 = b2f(h0[i]), v1 = b2f(h1r[i]), v2 = b2f(h2[i]);
      const float* w = wp + i * 3;
#pragma unroll
      for (int oo = 0; oo < 16; ++oo) {
        float a = acc[oo];
        a = fmaf(w[oo * 192 + 0], v0, a);
        a = fmaf(w[oo * 192 + 1], v1, a);
        a = fmaf(w[oo * 192 + 2], v2, a);
        acc[oo] = a;
      }
    }
#pragma unroll
    for (int oo = 0; oo < 16; ++oo) {
      float v = acc[oo];
      s += v; s2 += v * v;
      ot[(o0 + oo) * OST + lane] = f2b(v);
    }
  }
  red[0][wave][lane] = s;
  red[1][wave][lane] = s2;
  __syncthreads();

  // phase3: t uniform per iteration, o = tid -> fully coalesced global traffic
  int o = tid;
  float go = g2[o], bo = b2[o];
  const float* xg = x + (size_t)b * TT * DIMV + CC + o;
  float* ob = out + (size_t)b * TT * DIMV + CC + o;
  for (int t = 0; t < tw; ++t) {
    float sum  = red[0][0][t] + red[0][1][t] + red[0][2][t] + red[0][3][t];
    float sum2 = red[1][0][t] + red[1][1][t] + red[1][2][t] + red[1][3][t];
    float mean = sum * (1.f / 256.f);
    float var  = sum2 * (1.f / 256.f) - mean * mean;
    float rstd = rsqrtf(var + 1e-5f);
    float v = b2f(ot[o * OST + t]);
    float xn = (v - mean) * rstd * go + bo;
    float sg = 1.f / (1.f + expf(-xn));
    float xv = xg[(size_t)(t0 + t) * DIMV];
    ob[(size_t)(t0 + t) * DIMV] = xv * sg;
  }
}

// ---------------- launch ----------------

extern "C" void kernel_launch(void* const* d_in, const int* in_sizes, int n_in,
                              void* d_out, int out_size, void* d_ws, size_t ws_size,
                              hipStream_t stream) {
  const float* x  = (const float*)d_in[0];
  const float* lf = (const float*)d_in[1];
  const float* w1 = (const float*)d_in[2];
  const float* w2 = (const float*)d_in[3];
  const float* g1 = (const float*)d_in[4];
  const float* b1 = (const float*)d_in[5];
  const float* g2 = (const float*)d_in[6];
  const float* b2 = (const float*)d_in[7];
  float* out = (float*)d_out;

  char* ws = (char*)d_ws;
  float*    A   = (float*)(ws);                 // 122*243*2 f32 = 237 KB
  float*    Mt  = (float*)(ws + 262144);        // 243*243 f32   = 236 KB
  ushort_t* h1t = (ushort_t*)(ws + 524288);     // 512*128*243 bf16 = 31.9 MB

  k_compute_A<<<(FF * TT + 255) / 256, 256, 0, stream>>>(lf, A);
  k_compute_M<<<(TT * TT + 255) / 256, 256, 0, stream>>>(A, Mt);
  k_res<<<BB * 3, 256, 0, stream>>>(x, Mt, out);
  k_conv1<<<BB * 4, 256, 0, stream>>>(x, w1, g1, b1, h1t);
  k_conv2<<<BB * 4, 256, 0, stream>>>(x, h1t, w2, g2, b2, out);
}

// Round 3
// 324.112 us; speedup vs baseline: 19.2683x; 3.5645x over previous
//
#include <hip/hip_runtime.h>
#include <math.h>

typedef unsigned short ushort_t;
typedef unsigned int uint_t;
typedef __attribute__((ext_vector_type(8))) short short8v;   // 8 bf16 = 4 VGPR
typedef __attribute__((ext_vector_type(4))) float f32x4;

#define BB   512
#define TT   243
#define DIMV 512
#define CC   256
#define CHH  128
#define FF   122
#define NKK  122

__device__ __forceinline__ float b2f(ushort_t u) {
  union { uint_t i; float f; } z; z.i = ((uint_t)u) << 16; return z.f;
}
__device__ __forceinline__ ushort_t f2b(float f) {
  union { float f; uint_t i; } z; z.f = f;
  uint_t r = (z.i + 0x7fffu + ((z.i >> 16) & 1u)) >> 16;
  return (ushort_t)r;
}
__device__ __forceinline__ uint_t pack2(float a, float b) {
  return (uint_t)f2b(a) | ((uint_t)f2b(b) << 16);
}
union FragU { uint_t u[4]; short8v s; };

// ---------------- GlobalFilter prep ----------------

__global__ void k_compute_A(const float* __restrict__ lf, float* __restrict__ A) {
  int idx = blockIdx.x * 256 + threadIdx.x;
  if (idx >= FF * TT) return;
  int f = idx / TT, tp = idx - f * TT;
  float are = 0.f, aim = 0.f;
  for (int k = 0; k < NKK; ++k) {
    int m = (k * tp) % TT;
    float ph = -6.28318530717958647692f * (float)m / (float)TT;
    float s, c; sincosf(ph, &s, &c);
    float lr = lf[(f * NKK + k) * 2 + 0];
    float li = lf[(f * NKK + k) * 2 + 1];
    are = fmaf(lr, c, fmaf(-li, s, are));
    aim = fmaf(lr, s, fmaf(li, c, aim));
  }
  A[idx * 2 + 0] = are;
  A[idx * 2 + 1] = aim;
}

// F[t][tp] (256x256 zero-padded) written directly in MFMA A-fragment order:
// Ffrag[((kstep*16 + mtile)*64 + lane)*8 + j] = F[mtile*16 + lane%16][kstep*32 + (lane/16)*8 + j]
__global__ void k_compute_M(const float* __restrict__ A, ushort_t* __restrict__ Ffrag) {
  int idx = blockIdx.x * 256 + threadIdx.x;   // 65536
  int t = idx >> 8, tp = idx & 255;
  float val = 0.f;
  if (t < TT && tp < TT) {
    float acc = A[tp * 2 + 0];
    for (int f = 1; f < FF; ++f) {
      int m = (f * t) % TT;
      float ph = 6.28318530717958647692f * (float)m / (float)TT;
      float s, c; sincosf(ph, &s, &c);
      float ar = A[(f * TT + tp) * 2 + 0];
      float ai = A[(f * TT + tp) * 2 + 1];
      acc = fmaf(2.f * ar, c, fmaf(-2.f * ai, s, acc));
    }
    val = acc * (1.0f / (float)TT);
  }
  int kstep = tp >> 5, ko = tp & 31, p = ko >> 3, j = ko & 7;
  int mt = t >> 4, row = t & 15, lane = p * 16 + row;
  Ffrag[(((kstep * 16 + mt) * 64) + lane) * 8 + j] = f2b(val);
}

// pack conv weights into MFMA A-fragment order (bf16)
// w1frag: [g][ks 12][ot 4][lane][8]   k = ks*32+8*(l/16)+j ; dk=k>>7, i=k&127
// w2frag: [g][ks 6][ot 8][lane][8]    k = ks*32+8*(l/16)+j ; dk=k>>6, i=k&63
__global__ void k_prep_w(const float* __restrict__ w1, const float* __restrict__ w2,
                         ushort_t* __restrict__ w1f, ushort_t* __restrict__ w2f) {
  int q = blockIdx.x * 256 + threadIdx.x;
  if (q < 49152) {
    int j = q & 7, l = (q >> 3) & 63, ot = (q >> 9) & 3, rest = q >> 11;
    int ks = rest % 12, g = rest / 12;
    int o = ot * 16 + (l & 15);
    int k = ks * 32 + 8 * (l >> 4) + j;
    int dk = k >> 7, i = k & 127;
    w1f[q] = f2b(w1[(g * 64 + o) * 384 + i * 3 + dk]);
  } else if (q < 98304) {
    int q2 = q - 49152;
    int j = q2 & 7, l = (q2 >> 3) & 63, ot = (q2 >> 9) & 7, rest = q2 >> 12;
    int ks = rest % 6, g = rest / 6;
    int o = ot * 16 + (l & 15);
    int k = ks * 32 + 8 * (l >> 4) + j;
    int dk = k >> 6, i = k & 63;
    w2f[q2] = f2b(w2[(g * 128 + o) * 192 + i * 3 + dk]);
  }
}

// ---------------- res: out[b,t,c] = sum_tp F[t][tp] x[b][tp][c]  (MFMA) ----------------
// block = (b, c-chunk of 64). LDS x-tile transposed [c][k] bf16, 33-dword rows.

__global__ __launch_bounds__(256) void k_res(const float* __restrict__ x,
    const ushort_t* __restrict__ Ffrag, float* __restrict__ out) {
  __shared__ uint_t xs[2][64 * 33];
  int b = blockIdx.x >> 2, c0 = (blockIdx.x & 3) * 64;
  int tid = threadIdx.x, l = tid & 63, w = tid >> 6;
  const float* xb = x + (size_t)b * TT * DIMV + c0;
  const short8v* Fp = (const short8v*)Ffrag;

  f32x4 acc[4][4];
#pragma unroll
  for (int mi = 0; mi < 4; ++mi)
#pragma unroll
    for (int nt = 0; nt < 4; ++nt) acc[mi][nt] = (f32x4){0.f, 0.f, 0.f, 0.f};

  float v0[4], v1[4];
  int cc = tid & 63, kp0 = tid >> 6;   // per-thread: fixed c, kp = kp0 + 4*it

  // prologue: stage kstep 0
#pragma unroll
  for (int it = 0; it < 4; ++it) {
    int kp = kp0 + 4 * it, tp = 2 * kp;
    v0[it] = (tp < TT) ? xb[(size_t)tp * DIMV + cc] : 0.f;
    v1[it] = (tp + 1 < TT) ? xb[(size_t)(tp + 1) * DIMV + cc] : 0.f;
  }
#pragma unroll
  for (int it = 0; it < 4; ++it) xs[0][cc * 33 + kp0 + 4 * it] = pack2(v0[it], v1[it]);
  __syncthreads();

  for (int ks = 0; ks < 8; ++ks) {
    int cur = ks & 1;
    if (ks < 7) {
#pragma unroll
      for (int it = 0; it < 4; ++it) {
        int kp = kp0 + 4 * it, tp = (ks + 1) * 32 + 2 * kp;
        v0[it] = (tp < TT) ? xb[(size_t)tp * DIMV + cc] : 0.f;
        v1[it] = (tp + 1 < TT) ? xb[(size_t)(tp + 1) * DIMV + cc] : 0.f;
      }
    }
    // B fragments from LDS (4 dword reads each; rows 33 dw apart -> conflict-free)
    FragU bf[4];
#pragma unroll
    for (int nt = 0; nt < 4; ++nt) {
      int base = ((l & 15) + 16 * nt) * 33 + 4 * (l >> 4);
      const uint_t* pp = &xs[cur][base];
      bf[nt].u[0] = pp[0]; bf[nt].u[1] = pp[1]; bf[nt].u[2] = pp[2]; bf[nt].u[3] = pp[3];
    }
#pragma unroll
    for (int mi = 0; mi < 4; ++mi) {
      short8v af = Fp[(ks * 16 + (w * 4 + mi)) * 64 + l];
#pragma unroll
      for (int nt = 0; nt < 4; ++nt)
        acc[mi][nt] = __builtin_amdgcn_mfma_f32_16x16x32_bf16(af, bf[nt].s, acc[mi][nt], 0, 0, 0);
    }
    if (ks < 7) {
#pragma unroll
      for (int it = 0; it < 4; ++it) xs[cur ^ 1][cc * 33 + kp0 + 4 * it] = pack2(v0[it], v1[it]);
    }
    __syncthreads();
  }

  float* ob = out + (size_t)b * TT * DIMV + c0;
#pragma unroll
  for (int mi = 0; mi < 4; ++mi) {
    int tbase = (w * 4 + mi) * 16 + 4 * (l >> 4);
#pragma unroll
    for (int r = 0; r < 4; ++r) {
      int t = tbase + r;
      if (t < TT) {
#pragma unroll
        for (int nt = 0; nt < 4; ++nt)
          ob[(size_t)t * DIMV + nt * 16 + (l & 15)] = acc[mi][nt][r];
      }
    }
  }
}

// ---------------- conv1 + LN + gelu (MFMA) ----------------
// x gate half -> h1 [B][T][128] bf16. Block=(b, 64-t tile), 4 waves.

__global__ __launch_bounds__(256) void k_conv1(const float* __restrict__ x,
    const ushort_t* __restrict__ w1f, const float* __restrict__ g1, const float* __restrict__ b1,
    ushort_t* __restrict__ h1) {
  __shared__ uint_t xs[66 * 132];            // 66 rows x 264 bf16 (528B rows)
  __shared__ float red_s[4][64], red_s2[4][64];
  int b = blockIdx.x >> 2, t0 = (blockIdx.x & 3) * 64;
  int tid = threadIdx.x, l = tid & 63, w = tid >> 6;

  const float* xb = x + (size_t)b * TT * DIMV + CC;
#pragma unroll 4
  for (int it = 0; it < 33; ++it) {
    int e = tid + it * 256;
    int r = e >> 7, chp = e & 127;
    int t = t0 - 1 + r;
    float2 v = make_float2(0.f, 0.f);
    if (t >= 0 && t < TT) v = *(const float2*)&xb[(size_t)t * DIMV + 2 * chp];
    xs[r * 132 + chp] = pack2(v.x, v.y);
  }
  __syncthreads();

  int g = w >> 1;
  int gdw = g * 64;                          // channel offset in dwords (g*128 bf16)
  const short8v* w1p = (const short8v*)w1f;
  f32x4 acc[2][4];
#pragma unroll
  for (int a = 0; a < 2; ++a)
#pragma unroll
    for (int nt = 0; nt < 4; ++nt) acc[a][nt] = (f32x4){0.f, 0.f, 0.f, 0.f};

  for (int ks = 0; ks < 12; ++ks) {
    short8v af[2];
#pragma unroll
    for (int a = 0; a < 2; ++a)
      af[a] = w1p[((g * 12 + ks) * 4 + (w & 1) * 2 + a) * 64 + l];
    int dk = ks >> 2, i0dw = (ks & 3) * 16;  // (ks&3)*32 bf16
    FragU bf[4];
#pragma unroll
    for (int nt = 0; nt < 4; ++nt) {
      int row = (l & 15) + 16 * nt + dk;
      const uint4* pp = (const uint4*)&xs[row * 132 + gdw + i0dw + 4 * (l >> 4)];
      uint4 q = *pp;
      bf[nt].u[0] = q.x; bf[nt].u[1] = q.y; bf[nt].u[2] = q.z; bf[nt].u[3] = q.w;
    }
#pragma unroll
    for (int a = 0; a < 2; ++a)
#pragma unroll
      for (int nt = 0; nt < 4; ++nt)
        acc[a][nt] = __builtin_amdgcn_mfma_f32_16x16x32_bf16(af[a], bf[nt].s, acc[a][nt], 0, 0, 0);
  }

  // LN partials per t-column
  float s[4], s2[4];
#pragma unroll
  for (int nt = 0; nt < 4; ++nt) {
    float a0 = 0.f, a1 = 0.f;
#pragma unroll
    for (int a = 0; a < 2; ++a)
#pragma unroll
      for (int r = 0; r < 4; ++r) { float v = acc[a][nt][r]; a0 += v; a1 += v * v; }
    s[nt] = a0; s2[nt] = a1;
  }
#pragma unroll
  for (int nt = 0; nt < 4; ++nt) {
    s[nt] += __shfl_xor(s[nt], 16); s[nt] += __shfl_xor(s[nt], 32);
    s2[nt] += __shfl_xor(s2[nt], 16); s2[nt] += __shfl_xor(s2[nt], 32);
  }
  if (l < 16) {
#pragma unroll
    for (int nt = 0; nt < 4; ++nt) { red_s[w][nt * 16 + l] = s[nt]; red_s2[w][nt * 16 + l] = s2[nt]; }
  }
  __syncthreads();

  float mean[4], rstd[4];
#pragma unroll
  for (int nt = 0; nt < 4; ++nt) {
    int c = nt * 16 + (l & 15);
    float S = red_s[0][c] + red_s[1][c] + red_s[2][c] + red_s[3][c];
    float S2 = red_s2[0][c] + red_s2[1][c] + red_s2[2][c] + red_s2[3][c];
    float m = S * (1.f / 128.f);
    float var = S2 * (1.f / 128.f) - m * m;
    mean[nt] = m; rstd[nt] = rsqrtf(var + 1e-5f);
  }

  ushort_t* hb = h1 + (size_t)b * TT * CHH;
#pragma unroll
  for (int a = 0; a < 2; ++a) {
    int o0 = g * 64 + (w & 1) * 32 + a * 16 + 4 * (l >> 4);
    float4 gg = *(const float4*)&g1[o0];
    float4 bbv = *(const float4*)&b1[o0];
#pragma unroll
    for (int nt = 0; nt < 4; ++nt) {
      int t = t0 + (l & 15) + 16 * nt;
      if (t < TT) {
        float xn, ge; uint_t lo, hi;
        float gv[4] = {gg.x, gg.y, gg.z, gg.w};
        float bv[4] = {bbv.x, bbv.y, bbv.z, bbv.w};
        ushort_t h4[4];
#pragma unroll
        for (int r = 0; r < 4; ++r) {
          xn = (acc[a][nt][r] - mean[nt]) * rstd[nt] * gv[r] + bv[r];
          ge = 0.5f * xn * (1.f + erff(xn * 0.70710678118654752f));
          h4[r] = f2b(ge);
        }
        lo = (uint_t)h4[0] | ((uint_t)h4[1] << 16);
        hi = (uint_t)h4[2] | ((uint_t)h4[3] << 16);
        *(uint2*)&hb[(size_t)t * CHH + o0] = make_uint2(lo, hi);
      }
    }
  }
}

// ---------------- conv2 + LN + sigmoid + gate-mul (MFMA) ----------------

__global__ __launch_bounds__(256) void k_conv2(const float* __restrict__ x,
    const ushort_t* __restrict__ h1, const ushort_t* __restrict__ w2f,
    const float* __restrict__ g2, const float* __restrict__ b2, float* __restrict__ out) {
  __shared__ uint_t hs[66 * 68];             // 66 rows x 136 bf16 (272B rows)
  __shared__ ushort_t ot[64 * 264];          // raw conv out [t][o], 528B rows
  __shared__ float red_s[4][64], red_s2[4][64];
  int b = blockIdx.x >> 2, t0 = (blockIdx.x & 3) * 64;
  int tw = TT - t0; if (tw > 64) tw = 64;
  int tid = threadIdx.x, l = tid & 63, w = tid >> 6;

  const ushort_t* hbase = h1 + (size_t)b * TT * CHH;
#pragma unroll 4
  for (int it = 0; it < 17; ++it) {
    int e = tid + it * 256;
    if (e < 66 * 64) {
      int r = e >> 6, chp = e & 63;
      int t = t0 - 1 + r;
      uint_t v = 0;
      if (t >= 0 && t < TT) v = *(const uint_t*)&hbase[(size_t)t * CHH + 2 * chp];
      hs[r * 68 + chp] = v;
    }
  }
  __syncthreads();

  int g = w >> 1;
  int gdw = g * 32;                          // g*64 bf16
  const short8v* w2p = (const short8v*)w2f;
  f32x4 acc[4][4];
#pragma unroll
  for (int a = 0; a < 4; ++a)
#pragma unroll
    for (int nt = 0; nt < 4; ++nt) acc[a][nt] = (f32x4){0.f, 0.f, 0.f, 0.f};

  for (int ks = 0; ks < 6; ++ks) {
    short8v af[4];
#pragma unroll
    for (int a = 0; a < 4; ++a)
      af[a] = w2p[((g * 6 + ks) * 8 + (w & 1) * 4 + a) * 64 + l];
    int dk = ks >> 1, i0dw = (ks & 1) * 16;
    FragU bf[4];
#pragma unroll
    for (int nt = 0; nt < 4; ++nt) {
      int row = (l & 15) + 16 * nt + dk;
      const uint4* pp = (const uint4*)&hs[row * 68 + gdw + i0dw + 4 * (l >> 4)];
      uint4 q = *pp;
      bf[nt].u[0] = q.x; bf[nt].u[1] = q.y; bf[nt].u[2] = q.z; bf[nt].u[3] = q.w;
    }
#pragma unroll
    for (int a = 0; a < 4; ++a)
#pragma unroll
      for (int nt = 0; nt < 4; ++nt)
        acc[a][nt] = __builtin_amdgcn_mfma_f32_16x16x32_bf16(af[a], bf[nt].s, acc[a][nt], 0, 0, 0);
  }

  float s[4], s2[4];
#pragma unroll
  for (int nt = 0; nt < 4; ++nt) { s[nt] = 0.f; s2[nt] = 0.f; }
#pragma unroll
  for (int a = 0; a < 4; ++a) {
    int o0 = g * 128 + ((w & 1) * 4 + a) * 16 + 4 * (l >> 4);
#pragma unroll
    for (int nt = 0; nt < 4; ++nt) {
      int col = (l & 15) + 16 * nt;
      ushort_t h4[4];
#pragma unroll
      for (int r = 0; r < 4; ++r) {
        float v = acc[a][nt][r];
        s[nt] += v; s2[nt] += v * v;
        h4[r] = f2b(v);
      }
      uint_t lo = (uint_t)h4[0] | ((uint_t)h4[1] << 16);
      uint_t hi = (uint_t)h4[2] | ((uint_t)h4[3] << 16);
      *(uint2*)&ot[col * 264 + o0] = make_uint2(lo, hi);
    }
  }
#pragma unroll
  for (int nt = 0; nt < 4; ++nt) {
    s[nt] += __shfl_xor(s[nt], 16); s[nt] += __shfl_xor(s[nt], 32);
    s2[nt] += __shfl_xor(s2[nt], 16); s2[nt] += __shfl_xor(s2[nt], 32);
  }
  if (l < 16) {
#pragma unroll
    for (int nt = 0; nt < 4; ++nt) { red_s[w][nt * 16 + l] = s[nt]; red_s2[w][nt * 16 + l] = s2[nt]; }
  }
  __syncthreads();

  int o = tid;
  float gv = g2[o], bv = b2[o];
  const float* xg = x + (size_t)b * TT * DIMV + CC + o;
  float* ob = out + (size_t)b * TT * DIMV + CC + o;
  for (int t = 0; t < tw; ++t) {
    float S = red_s[0][t] + red_s[1][t] + red_s[2][t] + red_s[3][t];
    float S2 = red_s2[0][t] + red_s2[1][t] + red_s2[2][t] + red_s2[3][t];
    float m = S * (1.f / 256.f);
    float var = S2 * (1.f / 256.f) - m * m;
    float rstd = rsqrtf(var + 1e-5f);
    float v = b2f(ot[t * 264 + o]);
    float xn = (v - m) * rstd * gv + bv;
    float sg = 1.f / (1.f + expf(-xn));
    float xv = xg[(size_t)(t0 + t) * DIMV];
    ob[(size_t)(t0 + t) * DIMV] = xv * sg;
  }
}

// ---------------- launch ----------------

extern "C" void kernel_launch(void* const* d_in, const int* in_sizes, int n_in,
                              void* d_out, int out_size, void* d_ws, size_t ws_size,
                              hipStream_t stream) {
  const float* x  = (const float*)d_in[0];
  const float* lf = (const float*)d_in[1];
  const float* w1 = (const float*)d_in[2];
  const float* w2 = (const float*)d_in[3];
  const float* g1 = (const float*)d_in[4];
  const float* b1 = (const float*)d_in[5];
  const float* g2 = (const float*)d_in[6];
  const float* b2 = (const float*)d_in[7];
  float* out = (float*)d_out;

  char* ws = (char*)d_ws;
  float*    A     = (float*)(ws);                   // 237 KB
  ushort_t* Ffrag = (ushort_t*)(ws + 262144);       // 128 KB
  ushort_t* w1f   = (ushort_t*)(ws + 393216);       // 96 KB
  ushort_t* w2f   = (ushort_t*)(ws + 491520);       // 96 KB
  ushort_t* h1    = (ushort_t*)(ws + 589824);       // 31.85 MB

  k_compute_A<<<(FF * TT + 255) / 256, 256, 0, stream>>>(lf, A);
  k_compute_M<<<256, 256, 0, stream>>>(A, Ffrag);
  k_prep_w<<<384, 256, 0, stream>>>(w1, w2, w1f, w2f);
  k_res<<<BB * 4, 256, 0, stream>>>(x, Ffrag, out);
  k_conv1<<<BB * 4, 256, 0, stream>>>(x, w1f, g1, b1, h1);
  k_conv2<<<BB * 4, 256, 0, stream>>>(x, h1, w2f, g2, b2, out);
}

// Round 4
// 273.862 us; speedup vs baseline: 22.8037x; 1.1835x over previous
//
#include <hip/hip_runtime.h>
#include <math.h>

typedef unsigned short ushort_t;
typedef unsigned int uint_t;
typedef __attribute__((ext_vector_type(8))) short short8v;   // 8 bf16 = 4 VGPR
typedef __attribute__((ext_vector_type(4))) float f32x4;

#define BB   512
#define TT   243
#define DIMV 512
#define CC   256
#define CHH  128
#define FF   122
#define NKK  122

__device__ __forceinline__ float b2f(ushort_t u) {
  union { uint_t i; float f; } z; z.i = ((uint_t)u) << 16; return z.f;
}
__device__ __forceinline__ ushort_t f2b(float f) {
  union { float f; uint_t i; } z; z.f = f;
  uint_t r = (z.i + 0x7fffu + ((z.i >> 16) & 1u)) >> 16;
  return (ushort_t)r;
}
__device__ __forceinline__ uint_t pack2(float a, float b) {
  return (uint_t)f2b(a) | ((uint_t)f2b(b) << 16);
}
union FragU { uint_t u[4]; short8v s; };

// ---------------- GlobalFilter prep (LDS sincos table, incremental phase) ----------------

__global__ void k_compute_A(const float* __restrict__ lf, float* __restrict__ A) {
  __shared__ float2 tab[TT];
  int f = blockIdx.x;            // 0..121
  int tp = threadIdx.x;          // 0..255
  if (tp < TT) {
    float s, c;
    sincosf(6.28318530717958647692f * (float)tp / (float)TT, &s, &c);
    tab[tp] = make_float2(s, c);
  }
  __syncthreads();
  if (tp >= TT) return;
  float are = 0.f, aim = 0.f;
  int m = 0;
  const float* lrow = lf + (size_t)f * NKK * 2;
  for (int k = 0; k < NKK; ++k) {
    float2 sc = tab[m];
    float lr = lrow[2 * k], li = lrow[2 * k + 1];
    // phase = -2pi*k*tp/T: cos=+c, sin=-s
    are = fmaf(lr, sc.y, fmaf(li, sc.x, are));
    aim = fmaf(li, sc.y, fmaf(-lr, sc.x, aim));
    m += tp; if (m >= TT) m -= TT;
  }
  A[(f * TT + tp) * 2 + 0] = are;
  A[(f * TT + tp) * 2 + 1] = aim;
}

// F[t][tp] (256x256 zero-padded) written in MFMA fragment order:
// Ffrag[((kstep*16 + tt)*64 + lane)*8 + j] = F[tt*16 + lane%16][kstep*32 + (lane/16)*8 + j]
__global__ void k_compute_M(const float* __restrict__ A, ushort_t* __restrict__ Ffrag) {
  __shared__ float2 tab[TT];
  int t = blockIdx.x;            // 0..255
  int tp = threadIdx.x;          // 0..255
  if (tp < TT) {
    float s, c;
    sincosf(6.28318530717958647692f * (float)tp / (float)TT, &s, &c);
    tab[tp] = make_float2(s, c);
  }
  __syncthreads();
  float val = 0.f;
  if (t < TT && tp < TT) {
    float acc = A[tp * 2 + 0];                 // f=0 term
    int m = t;                                 // (1*t) % TT, t < TT
    for (int f = 1; f < FF; ++f) {
      float2 sc = tab[m];
      float ar = A[(f * TT + tp) * 2 + 0];
      float ai = A[(f * TT + tp) * 2 + 1];
      acc = fmaf(2.f * ar, sc.y, fmaf(-2.f * ai, sc.x, acc));
      m += t; if (m >= TT) m -= TT;
    }
    val = acc * (1.0f / (float)TT);
  }
  int kstep = tp >> 5, ko = tp & 31, p = ko >> 3, j = ko & 7;
  int mt = t >> 4, row = t & 15, lane = p * 16 + row;
  Ffrag[(((kstep * 16 + mt) * 64) + lane) * 8 + j] = f2b(val);
}

// pack conv weights into MFMA A-fragment order (bf16)
__global__ void k_prep_w(const float* __restrict__ w1, const float* __restrict__ w2,
                         ushort_t* __restrict__ w1f, ushort_t* __restrict__ w2f) {
  int q = blockIdx.x * 256 + threadIdx.x;
  if (q < 49152) {
    int j = q & 7, l = (q >> 3) & 63, ot = (q >> 9) & 3, rest = q >> 11;
    int ks = rest % 12, g = rest / 12;
    int o = ot * 16 + (l & 15);
    int k = ks * 32 + 8 * (l >> 4) + j;
    int dk = k >> 7, i = k & 127;
    w1f[q] = f2b(w1[(g * 64 + o) * 384 + i * 3 + dk]);
  } else if (q < 98304) {
    int q2 = q - 49152;
    int j = q2 & 7, l = (q2 >> 3) & 63, ot = (q2 >> 9) & 7, rest = q2 >> 12;
    int ks = rest % 6, g = rest / 6;
    int o = ot * 16 + (l & 15);
    int k = ks * 32 + 8 * (l >> 4) + j;
    int dk = k >> 6, i = k & 63;
    w2f[q2] = f2b(w2[(g * 128 + o) * 192 + i * 3 + dk]);
  }
}

// ---------------- res: out[b,t,c] = sum_tp F[t][tp] x[b][tp][c]  (MFMA, x as A) ----------------
// block = (b, c-chunk of 64). LDS x-tile [c][k] bf16, 33-dword rows.
// wave w owns N-tiles nt = 4w..4w+3 (t), all 4 M-tiles (c). C rows = c -> float4 stores.

__global__ __launch_bounds__(256) void k_res(const float* __restrict__ x,
    const ushort_t* __restrict__ Ffrag, float* __restrict__ out) {
  __shared__ uint_t xs[2][64 * 33];
  int b = blockIdx.x >> 2, c0 = (blockIdx.x & 3) * 64;
  int tid = threadIdx.x, l = tid & 63, w = tid >> 6;
  const float* xb = x + (size_t)b * TT * DIMV + c0;
  const short8v* Fp = (const short8v*)Ffrag;

  f32x4 acc[4][4];                             // [q = nt-local][m]
#pragma unroll
  for (int q = 0; q < 4; ++q)
#pragma unroll
    for (int m = 0; m < 4; ++m) acc[q][m] = (f32x4){0.f, 0.f, 0.f, 0.f};

  float v0[4], v1[4];
  int cc = tid & 63, kp0 = tid >> 6;

#pragma unroll
  for (int it = 0; it < 4; ++it) {
    int kp = kp0 + 4 * it, tp = 2 * kp;
    v0[it] = (tp < TT) ? xb[(size_t)tp * DIMV + cc] : 0.f;
    v1[it] = (tp + 1 < TT) ? xb[(size_t)(tp + 1) * DIMV + cc] : 0.f;
  }
#pragma unroll
  for (int it = 0; it < 4; ++it) xs[0][cc * 33 + kp0 + 4 * it] = pack2(v0[it], v1[it]);
  __syncthreads();

  for (int ks = 0; ks < 8; ++ks) {
    int cur = ks & 1;
    if (ks < 7) {
#pragma unroll
      for (int it = 0; it < 4; ++it) {
        int kp = kp0 + 4 * it, tp = (ks + 1) * 32 + 2 * kp;
        v0[it] = (tp < TT) ? xb[(size_t)tp * DIMV + cc] : 0.f;
        v1[it] = (tp + 1 < TT) ? xb[(size_t)(tp + 1) * DIMV + cc] : 0.f;
      }
    }
    // B frags: F for this wave's 4 nt tiles (global, L2-resident, disjoint per wave)
    FragU bfr[4];
#pragma unroll
    for (int q = 0; q < 4; ++q) {
      short8v v = Fp[(ks * 16 + 4 * w + q) * 64 + l];
      bfr[q].s = v;
    }
    // A frags from LDS per m-tile, then MFMA
#pragma unroll
    for (int m = 0; m < 4; ++m) {
      FragU af;
      const uint_t* pp = &xs[cur][(16 * m + (l & 15)) * 33 + 4 * (l >> 4)];
      af.u[0] = pp[0]; af.u[1] = pp[1]; af.u[2] = pp[2]; af.u[3] = pp[3];
#pragma unroll
      for (int q = 0; q < 4; ++q)
        acc[q][m] = __builtin_amdgcn_mfma_f32_16x16x32_bf16(af.s, bfr[q].s, acc[q][m], 0, 0, 0);
    }
    if (ks < 7) {
#pragma unroll
      for (int it = 0; it < 4; ++it) xs[cur ^ 1][cc * 33 + kp0 + 4 * it] = pack2(v0[it], v1[it]);
    }
    __syncthreads();
  }

  float* ob = out + (size_t)b * TT * DIMV + c0;
#pragma unroll
  for (int q = 0; q < 4; ++q) {
    int t = (4 * w + q) * 16 + (l & 15);
    if (t < TT) {
#pragma unroll
      for (int m = 0; m < 4; ++m)
        *(f32x4*)&ob[(size_t)t * DIMV + 16 * m + 4 * (l >> 4)] = acc[q][m];
    }
  }
}

// ---------------- fused gate: conv1+LN+gelu -> LDS -> conv2+LN+sigmoid+mul ----------------
// block = (b, 64-t tile). xs halo rows t0-2..t0+65 (68). h computed for t0-1..t0+64 (66 rows).

#define XROWS 68
#define XSTD  132   // dwords per xs row (256 bf16 + pad)
#define HROWS 66
#define HSTD  68    // dwords per hs row (128 bf16 + pad)

__global__ __launch_bounds__(256) void k_gate(const float* __restrict__ x,
    const ushort_t* __restrict__ w1f, const float* __restrict__ g1, const float* __restrict__ b1,
    const ushort_t* __restrict__ w2f, const float* __restrict__ g2, const float* __restrict__ b2,
    float* __restrict__ out) {
  __shared__ uint_t xs[XROWS * XSTD];          // 35.9 KB
  __shared__ uint_t hs[HROWS * HSTD];          // 17.9 KB
  __shared__ float red1s[4][80], red1q[4][80];
  __shared__ float red2s[4][64], red2q[4][64];
  int b = blockIdx.x >> 2, t0 = (blockIdx.x & 3) * 64;
  int tid = threadIdx.x, l = tid & 63, w = tid >> 6;
  int g = w >> 1, half = w & 1;

  // ---- stage x gate half, rows t0-2 .. t0+65, bf16 ----
  const float* xb = x + (size_t)b * TT * DIMV + CC;
#pragma unroll 4
  for (int it = 0; it < 34; ++it) {
    int e = tid + it * 256;
    int r = e >> 7, chp = e & 127;
    int t = t0 - 2 + r;
    float2 v = make_float2(0.f, 0.f);
    if (t >= 0 && t < TT) v = *(const float2*)&xb[(size_t)t * DIMV + 2 * chp];
    xs[r * XSTD + chp] = pack2(v.x, v.y);
  }
  __syncthreads();

  // ---- conv1: M=128 o, N=80 cols (c=0..79 ; t_out = t0-1+c), K=384 ----
  const short8v* w1p = (const short8v*)w1f;
  int gdw = g * 64;                            // input-channel offset (dwords)
  f32x4 acc1[2][5];
#pragma unroll
  for (int a = 0; a < 2; ++a)
#pragma unroll
    for (int nt = 0; nt < 5; ++nt) acc1[a][nt] = (f32x4){0.f, 0.f, 0.f, 0.f};

  for (int ks = 0; ks < 12; ++ks) {
    short8v af[2];
#pragma unroll
    for (int a = 0; a < 2; ++a)
      af[a] = w1p[((g * 12 + ks) * 4 + half * 2 + a) * 64 + l];
    int dk = ks >> 2, i0dw = (ks & 3) * 16;
    FragU bf[5];
#pragma unroll
    for (int nt = 0; nt < 5; ++nt) {
      int row = (l & 15) + 16 * nt + dk;       // input row = c + dk
      if (nt == 4) row = row > (XROWS - 1) ? (XROWS - 1) : row;   // clamp (cols 66..79 unused)
      const uint4* pp = (const uint4*)&xs[row * XSTD + gdw + i0dw + 4 * (l >> 4)];
      uint4 qv = *pp;
      bf[nt].u[0] = qv.x; bf[nt].u[1] = qv.y; bf[nt].u[2] = qv.z; bf[nt].u[3] = qv.w;
    }
#pragma unroll
    for (int a = 0; a < 2; ++a)
#pragma unroll
      for (int nt = 0; nt < 5; ++nt)
        acc1[a][nt] = __builtin_amdgcn_mfma_f32_16x16x32_bf16(af[a], bf[nt].s, acc1[a][nt], 0, 0, 0);
  }

  // ---- LN1 stats per col ----
#pragma unroll
  for (int nt = 0; nt < 5; ++nt) {
    float s = 0.f, s2 = 0.f;
#pragma unroll
    for (int a = 0; a < 2; ++a)
#pragma unroll
      for (int r = 0; r < 4; ++r) { float v = acc1[a][nt][r]; s += v; s2 += v * v; }
    s += __shfl_xor(s, 16); s += __shfl_xor(s, 32);
    s2 += __shfl_xor(s2, 16); s2 += __shfl_xor(s2, 32);
    if (l < 16) { red1s[w][l + 16 * nt] = s; red1q[w][l + 16 * nt] = s2; }
  }
  __syncthreads();

  // ---- apply LN1 + gelu, write h (bf16) to hs ----
#pragma unroll
  for (int nt = 0; nt < 5; ++nt) {
    int c = (l & 15) + 16 * nt;
    if (c < HROWS) {
      int t_out = t0 - 1 + c;
      bool valid = (t_out >= 0 && t_out < TT);
      float S = red1s[0][c] + red1s[1][c] + red1s[2][c] + red1s[3][c];
      float S2 = red1q[0][c] + red1q[1][c] + red1q[2][c] + red1q[3][c];
      float mean = S * (1.f / 128.f);
      float var = S2 * (1.f / 128.f) - mean * mean;
      float rstd = rsqrtf(var + 1e-5f);
#pragma unroll
      for (int a = 0; a < 2; ++a) {
        int o0 = g * 64 + half * 32 + a * 16 + 4 * (l >> 4);
        float4 gg = *(const float4*)&g1[o0];
        float4 bb = *(const float4*)&b1[o0];
        float gv[4] = {gg.x, gg.y, gg.z, gg.w};
        float bv[4] = {bb.x, bb.y, bb.z, bb.w};
        ushort_t h4[4];
#pragma unroll
        for (int r = 0; r < 4; ++r) {
          float xn = (acc1[a][nt][r] - mean) * rstd * gv[r] + bv[r];
          float ge = 0.5f * xn * (1.f + erff(xn * 0.70710678118654752f));
          h4[r] = valid ? f2b(ge) : (ushort_t)0;
        }
        uint_t lo = (uint_t)h4[0] | ((uint_t)h4[1] << 16);
        uint_t hi = (uint_t)h4[2] | ((uint_t)h4[3] << 16);
        *(uint2*)&hs[c * HSTD + (o0 >> 1)] = make_uint2(lo, hi);
      }
    }
  }
  __syncthreads();

  // ---- conv2: M=256 o, N=64 t, K=192 ----
  const short8v* w2p = (const short8v*)w2f;
  int gdw2 = g * 32;                           // h-channel offset (dwords)
  f32x4 acc2[4][4];
#pragma unroll
  for (int a = 0; a < 4; ++a)
#pragma unroll
    for (int nt = 0; nt < 4; ++nt) acc2[a][nt] = (f32x4){0.f, 0.f, 0.f, 0.f};

  for (int ks = 0; ks < 6; ++ks) {
    short8v af[4];
#pragma unroll
    for (int a = 0; a < 4; ++a)
      af[a] = w2p[((g * 6 + ks) * 8 + half * 4 + a) * 64 + l];
    int dk = ks >> 1, i0dw = (ks & 1) * 16;
    FragU bf[4];
#pragma unroll
    for (int nt = 0; nt < 4; ++nt) {
      int row = (l & 15) + 16 * nt + dk;       // hs row = (t - t0) + dk, <= 65
      const uint4* pp = (const uint4*)&hs[row * HSTD + gdw2 + i0dw + 4 * (l >> 4)];
      uint4 qv = *pp;
      bf[nt].u[0] = qv.x; bf[nt].u[1] = qv.y; bf[nt].u[2] = qv.z; bf[nt].u[3] = qv.w;
    }
#pragma unroll
    for (int a = 0; a < 4; ++a)
#pragma unroll
      for (int nt = 0; nt < 4; ++nt)
        acc2[a][nt] = __builtin_amdgcn_mfma_f32_16x16x32_bf16(af[a], bf[nt].s, acc2[a][nt], 0, 0, 0);
  }

  // ---- LN2 stats ----
#pragma unroll
  for (int nt = 0; nt < 4; ++nt) {
    float s = 0.f, s2 = 0.f;
#pragma unroll
    for (int a = 0; a < 4; ++a)
#pragma unroll
      for (int r = 0; r < 4; ++r) { float v = acc2[a][nt][r]; s += v; s2 += v * v; }
    s += __shfl_xor(s, 16); s += __shfl_xor(s, 32);
    s2 += __shfl_xor(s2, 16); s2 += __shfl_xor(s2, 32);
    if (l < 16) { red2s[w][l + 16 * nt] = s; red2q[w][l + 16 * nt] = s2; }
  }
  __syncthreads();

  // ---- apply LN2 + sigmoid + gate-mul, float4 stores ----
  float* ob = out + (size_t)b * TT * DIMV + CC;
#pragma unroll
  for (int nt = 0; nt < 4; ++nt) {
    int c = (l & 15) + 16 * nt;
    int t = t0 + c;
    if (t < TT) {
      float S = red2s[0][c] + red2s[1][c] + red2s[2][c] + red2s[3][c];
      float S2 = red2q[0][c] + red2q[1][c] + red2q[2][c] + red2q[3][c];
      float mean = S * (1.f / 256.f);
      float var = S2 * (1.f / 256.f) - mean * mean;
      float rstd = rsqrtf(var + 1e-5f);
      int xrow = c + 2;                        // xs row for t
#pragma unroll
      for (int a = 0; a < 4; ++a) {
        int o0 = g * 128 + (half * 4 + a) * 16 + 4 * (l >> 4);
        float4 gg = *(const float4*)&g2[o0];
        float4 bb = *(const float4*)&b2[o0];
        float gv[4] = {gg.x, gg.y, gg.z, gg.w};
        float bv[4] = {bb.x, bb.y, bb.z, bb.w};
        uint2 xv2 = *(const uint2*)&xs[xrow * XSTD + (o0 >> 1)];
        float xvv[4] = { b2f((ushort_t)(xv2.x & 0xffff)), b2f((ushort_t)(xv2.x >> 16)),
                         b2f((ushort_t)(xv2.y & 0xffff)), b2f((ushort_t)(xv2.y >> 16)) };
        f32x4 res;
#pragma unroll
        for (int r = 0; r < 4; ++r) {
          float xn = (acc2[a][nt][r] - mean) * rstd * gv[r] + bv[r];
          float sg = 1.f / (1.f + expf(-xn));
          res[r] = xvv[r] * sg;
        }
        *(f32x4*)&ob[(size_t)t * DIMV + o0] = res;
      }
    }
  }
}

// ---------------- launch ----------------

extern "C" void kernel_launch(void* const* d_in, const int* in_sizes, int n_in,
                              void* d_out, int out_size, void* d_ws, size_t ws_size,
                              hipStream_t stream) {
  const float* x  = (const float*)d_in[0];
  const float* lf = (const float*)d_in[1];
  const float* w1 = (const float*)d_in[2];
  const float* w2 = (const float*)d_in[3];
  const float* g1 = (const float*)d_in[4];
  const float* b1 = (const float*)d_in[5];
  const float* g2 = (const float*)d_in[6];
  const float* b2 = (const float*)d_in[7];
  float* out = (float*)d_out;

  char* ws = (char*)d_ws;
  float*    A     = (float*)(ws);                   // 237 KB
  ushort_t* Ffrag = (ushort_t*)(ws + 262144);       // 128 KB
  ushort_t* w1f   = (ushort_t*)(ws + 393216);       // 96 KB
  ushort_t* w2f   = (ushort_t*)(ws + 491520);       // 96 KB

  k_compute_A<<<FF, 256, 0, stream>>>(lf, A);
  k_compute_M<<<256, 256, 0, stream>>>(A, Ffrag);
  k_prep_w<<<384, 256, 0, stream>>>(w1, w2, w1f, w2f);
  k_res<<<BB * 4, 256, 0, stream>>>(x, Ffrag, out);
  k_gate<<<BB * 4, 256, 0, stream>>>(x, w1f, g1, b1, w2f, g2, b2, out);
}

// Round 5
// 234.840 us; speedup vs baseline: 26.5929x; 1.1662x over previous
//
#include <hip/hip_runtime.h>
#include <math.h>

typedef unsigned short ushort_t;
typedef unsigned int uint_t;
typedef __attribute__((ext_vector_type(8))) short short8v;   // 8 bf16 = 4 VGPR
typedef __attribute__((ext_vector_type(4))) float f32x4;

#define BB   512
#define TT   243
#define DIMV 512
#define CC   256
#define CHH  128
#define FF   122
#define NKK  122

__device__ __forceinline__ float b2f(ushort_t u) {
  union { uint_t i; float f; } z; z.i = ((uint_t)u) << 16; return z.f;
}
__device__ __forceinline__ ushort_t f2b(float f) {
  union { float f; uint_t i; } z; z.f = f;
  uint_t r = (z.i + 0x7fffu + ((z.i >> 16) & 1u)) >> 16;
  return (ushort_t)r;
}
// packed f32x2 -> bf16x2 in one VALU instr (RNE)
__device__ __forceinline__ uint_t pack2(float a, float b) {
  uint_t r;
  asm("v_cvt_pk_bf16_f32 %0, %1, %2" : "=v"(r) : "v"(a), "v"(b));
  return r;
}
// branchless exact-enough gelu: A&S 7.1.26 erf, |eps|<=1.5e-7
__device__ __forceinline__ float gelu_f(float x) {
  float z = fabsf(x) * 0.70710678118654752f;
  float t = __builtin_amdgcn_rcpf(fmaf(0.3275911f, z, 1.0f));
  float p = fmaf(1.061405429f, t, -1.453152027f);
  p = fmaf(p, t, 1.421413741f);
  p = fmaf(p, t, -0.284496736f);
  p = fmaf(p, t, 0.254829592f);
  p = p * t;
  float e = __expf(-z * z);
  float erfa = 1.0f - p * e;
  float erfs = copysignf(erfa, x);
  return 0.5f * x * (1.0f + erfs);
}
__device__ __forceinline__ float sigmoid_f(float x) {
  return __builtin_amdgcn_rcpf(1.0f + __expf(-x));
}
union FragU { uint_t u[4]; short8v s; };

// ---------------- GlobalFilter prep (LDS sincos table, incremental phase) ----------------

__global__ void k_compute_A(const float* __restrict__ lf, float* __restrict__ A) {
  __shared__ float2 tab[TT];
  int f = blockIdx.x;            // 0..121
  int tp = threadIdx.x;          // 0..255
  if (tp < TT) {
    float s, c;
    sincosf(6.28318530717958647692f * (float)tp / (float)TT, &s, &c);
    tab[tp] = make_float2(s, c);
  }
  __syncthreads();
  if (tp >= TT) return;
  float are = 0.f, aim = 0.f;
  int m = 0;
  const float* lrow = lf + (size_t)f * NKK * 2;
  for (int k = 0; k < NKK; ++k) {
    float2 sc = tab[m];
    float lr = lrow[2 * k], li = lrow[2 * k + 1];
    are = fmaf(lr, sc.y, fmaf(li, sc.x, are));
    aim = fmaf(li, sc.y, fmaf(-lr, sc.x, aim));
    m += tp; if (m >= TT) m -= TT;
  }
  A[(f * TT + tp) * 2 + 0] = are;
  A[(f * TT + tp) * 2 + 1] = aim;
}

// F[t][tp] (256x256 zero-padded) in MFMA fragment order:
// Ffrag[((kstep*16 + mt)*64 + lane)*8 + j] = F[mt*16 + lane%16][kstep*32 + (lane/16)*8 + j]
__global__ void k_compute_M(const float* __restrict__ A, ushort_t* __restrict__ Ffrag) {
  __shared__ float2 tab[TT];
  int t = blockIdx.x;            // 0..255
  int tp = threadIdx.x;          // 0..255
  if (tp < TT) {
    float s, c;
    sincosf(6.28318530717958647692f * (float)tp / (float)TT, &s, &c);
    tab[tp] = make_float2(s, c);
  }
  __syncthreads();
  float val = 0.f;
  if (t < TT && tp < TT) {
    float acc = A[tp * 2 + 0];
    int m = t;
    for (int f = 1; f < FF; ++f) {
      float2 sc = tab[m];
      float ar = A[(f * TT + tp) * 2 + 0];
      float ai = A[(f * TT + tp) * 2 + 1];
      acc = fmaf(2.f * ar, sc.y, fmaf(-2.f * ai, sc.x, acc));
      m += t; if (m >= TT) m -= TT;
    }
    val = acc * (1.0f / (float)TT);
  }
  int kstep = tp >> 5, ko = tp & 31, p = ko >> 3, j = ko & 7;
  int mt = t >> 4, row = t & 15, lane = p * 16 + row;
  Ffrag[(((kstep * 16 + mt) * 64) + lane) * 8 + j] = f2b(val);
}

// pack conv weights into MFMA A-fragment order (bf16)
__global__ void k_prep_w(const float* __restrict__ w1, const float* __restrict__ w2,
                         ushort_t* __restrict__ w1f, ushort_t* __restrict__ w2f) {
  int q = blockIdx.x * 256 + threadIdx.x;
  if (q < 49152) {
    int j = q & 7, l = (q >> 3) & 63, ot = (q >> 9) & 3, rest = q >> 11;
    int ks = rest % 12, g = rest / 12;
    int o = ot * 16 + (l & 15);
    int k = ks * 32 + 8 * (l >> 4) + j;
    int dk = k >> 7, i = k & 127;
    w1f[q] = f2b(w1[(g * 64 + o) * 384 + i * 3 + dk]);
  } else if (q < 98304) {
    int q2 = q - 49152;
    int j = q2 & 7, l = (q2 >> 3) & 63, ot = (q2 >> 9) & 7, rest = q2 >> 12;
    int ks = rest % 6, g = rest / 6;
    int o = ot * 16 + (l & 15);
    int k = ks * 32 + 8 * (l >> 4) + j;
    int dk = k >> 6, i = k & 63;
    w2f[q2] = f2b(w2[(g * 128 + o) * 192 + i * 3 + dk]);
  }
}

// ---------------- res: out[b,t,c] = sum_tp F[t][tp] x[b][tp][c]  (MFMA, x as A) ----------------
// block = (b, c-chunk of 64). LDS x-tile [c][k] bf16, 17-dword rows (8.7 KB total).

#define RST 17
__global__ __launch_bounds__(256) void k_res(const float* __restrict__ x,
    const ushort_t* __restrict__ Ffrag, float* __restrict__ out) {
  __shared__ uint_t xs[2][64 * RST];
  int b = blockIdx.x >> 2, c0 = (blockIdx.x & 3) * 64;
  int tid = threadIdx.x, l = tid & 63, w = tid >> 6;
  const float* xb = x + (size_t)b * TT * DIMV + c0;
  const short8v* Fp = (const short8v*)Ffrag;

  f32x4 acc[4][4];                             // [q = nt-local][m]
#pragma unroll
  for (int q = 0; q < 4; ++q)
#pragma unroll
    for (int m = 0; m < 4; ++m) acc[q][m] = (f32x4){0.f, 0.f, 0.f, 0.f};

  float v0[4], v1[4];
  int cc = tid & 63, kp0 = tid >> 6;

#pragma unroll
  for (int it = 0; it < 4; ++it) {
    int kp = kp0 + 4 * it, tp = 2 * kp;
    v0[it] = (tp < TT) ? xb[(size_t)tp * DIMV + cc] : 0.f;
    v1[it] = (tp + 1 < TT) ? xb[(size_t)(tp + 1) * DIMV + cc] : 0.f;
  }
#pragma unroll
  for (int it = 0; it < 4; ++it) xs[0][cc * RST + kp0 + 4 * it] = pack2(v0[it], v1[it]);
  __syncthreads();

  for (int ks = 0; ks < 8; ++ks) {
    int cur = ks & 1;
    if (ks < 7) {
#pragma unroll
      for (int it = 0; it < 4; ++it) {
        int kp = kp0 + 4 * it, tp = (ks + 1) * 32 + 2 * kp;
        v0[it] = (tp < TT) ? xb[(size_t)tp * DIMV + cc] : 0.f;
        v1[it] = (tp + 1 < TT) ? xb[(size_t)(tp + 1) * DIMV + cc] : 0.f;
      }
    }
    FragU bfr[4];
#pragma unroll
    for (int q = 0; q < 4; ++q) bfr[q].s = Fp[(ks * 16 + 4 * w + q) * 64 + l];
#pragma unroll
    for (int m = 0; m < 4; ++m) {
      FragU af;
      const uint_t* pp = &xs[cur][(16 * m + (l & 15)) * RST + 4 * (l >> 4)];
      af.u[0] = pp[0]; af.u[1] = pp[1]; af.u[2] = pp[2]; af.u[3] = pp[3];
#pragma unroll
      for (int q = 0; q < 4; ++q)
        acc[q][m] = __builtin_amdgcn_mfma_f32_16x16x32_bf16(af.s, bfr[q].s, acc[q][m], 0, 0, 0);
    }
    if (ks < 7) {
#pragma unroll
      for (int it = 0; it < 4; ++it) xs[cur ^ 1][cc * RST + kp0 + 4 * it] = pack2(v0[it], v1[it]);
    }
    __syncthreads();
  }

  float* ob = out + (size_t)b * TT * DIMV + c0;
#pragma unroll
  for (int q = 0; q < 4; ++q) {
    int t = (4 * w + q) * 16 + (l & 15);
    if (t < TT) {
#pragma unroll
      for (int m = 0; m < 4; ++m)
        *(f32x4*)&ob[(size_t)t * DIMV + 16 * m + 4 * (l >> 4)] = acc[q][m];
    }
  }
}

// ---------------- fused gate: conv1+LN+gelu -> LDS -> conv2+LN+sigmoid+mul ----------------
// block = (b, 32-t tile). xs rows t0-2..t0+33 (36). h rows t0-1..t0+32 (34).

#define BT    32
#define NTIL  8     // ceil(243/32)
#define XROWS 36
#define XSTD  132   // dwords per xs row (256 bf16 + pad)
#define HROWS 34
#define HSTD  68    // dwords per hs row (128 bf16 + pad)

__global__ __launch_bounds__(256) void k_gate(const float* __restrict__ x,
    const ushort_t* __restrict__ w1f, const float* __restrict__ g1, const float* __restrict__ b1,
    const ushort_t* __restrict__ w2f, const float* __restrict__ g2, const float* __restrict__ b2,
    float* __restrict__ out) {
  __shared__ uint_t xs[XROWS * XSTD];          // 19.0 KB
  __shared__ uint_t hs[HROWS * HSTD];          // 9.2 KB
  __shared__ float red1s[4][48], red1q[4][48]; // 1.5 KB
  __shared__ float red2s[4][32], red2q[4][32]; // 1.0 KB
  int b = blockIdx.x >> 3, t0 = (blockIdx.x & 7) * BT;
  int tid = threadIdx.x, l = tid & 63, w = tid >> 6;
  int g = w >> 1, half = w & 1;

  // ---- stage x gate half, rows t0-2 .. t0+33, bf16, float4 loads ----
  const float* xb = x + (size_t)b * TT * DIMV + CC;
#pragma unroll 3
  for (int it = 0; it < 9; ++it) {
    int e = tid + it * 256;                    // 36*64 quad-chunks
    int r = e >> 6, cq = e & 63;               // cq: 4-channel chunk
    int t = t0 - 2 + r;
    float4 v = make_float4(0.f, 0.f, 0.f, 0.f);
    if (t >= 0 && t < TT) v = *(const float4*)&xb[(size_t)t * DIMV + 4 * cq];
    *(uint2*)&xs[r * XSTD + 2 * cq] = make_uint2(pack2(v.x, v.y), pack2(v.z, v.w));
  }
  __syncthreads();

  // ---- conv1: M=128 o, N=48 cols (c=0..47; t_out = t0-1+c, valid c<34), K=384 ----
  const short8v* w1p = (const short8v*)w1f;
  int gdw = g * 64;
  f32x4 acc1[2][3];
#pragma unroll
  for (int a = 0; a < 2; ++a)
#pragma unroll
    for (int nt = 0; nt < 3; ++nt) acc1[a][nt] = (f32x4){0.f, 0.f, 0.f, 0.f};

  for (int ks = 0; ks < 12; ++ks) {
    short8v af[2];
#pragma unroll
    for (int a = 0; a < 2; ++a)
      af[a] = w1p[((g * 12 + ks) * 4 + half * 2 + a) * 64 + l];
    int dk = ks >> 2, i0dw = (ks & 3) * 16;
    FragU bf[3];
#pragma unroll
    for (int nt = 0; nt < 3; ++nt) {
      int row = (l & 15) + 16 * nt + dk;
      if (nt == 2) row = row > (XROWS - 1) ? (XROWS - 1) : row;  // cols >=34 are garbage
      const uint4* pp = (const uint4*)&xs[row * XSTD + gdw + i0dw + 4 * (l >> 4)];
      uint4 qv = *pp;
      bf[nt].u[0] = qv.x; bf[nt].u[1] = qv.y; bf[nt].u[2] = qv.z; bf[nt].u[3] = qv.w;
    }
#pragma unroll
    for (int a = 0; a < 2; ++a)
#pragma unroll
      for (int nt = 0; nt < 3; ++nt)
        acc1[a][nt] = __builtin_amdgcn_mfma_f32_16x16x32_bf16(af[a], bf[nt].s, acc1[a][nt], 0, 0, 0);
  }

  // ---- LN1 stats per col ----
#pragma unroll
  for (int nt = 0; nt < 3; ++nt) {
    float s = 0.f, s2 = 0.f;
#pragma unroll
    for (int a = 0; a < 2; ++a)
#pragma unroll
      for (int r = 0; r < 4; ++r) { float v = acc1[a][nt][r]; s += v; s2 += v * v; }
    s += __shfl_xor(s, 16); s += __shfl_xor(s, 32);
    s2 += __shfl_xor(s2, 16); s2 += __shfl_xor(s2, 32);
    if (l < 16) { red1s[w][l + 16 * nt] = s; red1q[w][l + 16 * nt] = s2; }
  }
  __syncthreads();

  // ---- apply LN1 + gelu, write h (bf16) to hs ----
#pragma unroll
  for (int nt = 0; nt < 3; ++nt) {
    int c = (l & 15) + 16 * nt;
    if (c < HROWS) {
      int t_out = t0 - 1 + c;
      bool valid = (t_out >= 0 && t_out < TT);
      float S = red1s[0][c] + red1s[1][c] + red1s[2][c] + red1s[3][c];
      float S2 = red1q[0][c] + red1q[1][c] + red1q[2][c] + red1q[3][c];
      float mean = S * (1.f / 128.f);
      float var = S2 * (1.f / 128.f) - mean * mean;
      float rstd = rsqrtf(var + 1e-5f);
#pragma unroll
      for (int a = 0; a < 2; ++a) {
        int o0 = g * 64 + half * 32 + a * 16 + 4 * (l >> 4);
        float4 gg = *(const float4*)&g1[o0];
        float4 bb = *(const float4*)&b1[o0];
        float gv[4] = {gg.x, gg.y, gg.z, gg.w};
        float bv[4] = {bb.x, bb.y, bb.z, bb.w};
        float h4[4];
#pragma unroll
        for (int r = 0; r < 4; ++r) {
          float xn = (acc1[a][nt][r] - mean) * rstd * gv[r] + bv[r];
          h4[r] = valid ? gelu_f(xn) : 0.f;
        }
        *(uint2*)&hs[c * HSTD + (o0 >> 1)] =
            make_uint2(pack2(h4[0], h4[1]), pack2(h4[2], h4[3]));
      }
    }
  }
  __syncthreads();

  // ---- conv2: M=256 o, N=32 t, K=192 ----
  const short8v* w2p = (const short8v*)w2f;
  int gdw2 = g * 32;
  f32x4 acc2[4][2];
#pragma unroll
  for (int a = 0; a < 4; ++a)
#pragma unroll
    for (int nt = 0; nt < 2; ++nt) acc2[a][nt] = (f32x4){0.f, 0.f, 0.f, 0.f};

  for (int ks = 0; ks < 6; ++ks) {
    short8v af[4];
#pragma unroll
    for (int a = 0; a < 4; ++a)
      af[a] = w2p[((g * 6 + ks) * 8 + half * 4 + a) * 64 + l];
    int dk = ks >> 1, i0dw = (ks & 1) * 16;
    FragU bf[2];
#pragma unroll
    for (int nt = 0; nt < 2; ++nt) {
      int row = (l & 15) + 16 * nt + dk;       // <= 33
      const uint4* pp = (const uint4*)&hs[row * HSTD + gdw2 + i0dw + 4 * (l >> 4)];
      uint4 qv = *pp;
      bf[nt].u[0] = qv.x; bf[nt].u[1] = qv.y; bf[nt].u[2] = qv.z; bf[nt].u[3] = qv.w;
    }
#pragma unroll
    for (int a = 0; a < 4; ++a)
#pragma unroll
      for (int nt = 0; nt < 2; ++nt)
        acc2[a][nt] = __builtin_amdgcn_mfma_f32_16x16x32_bf16(af[a], bf[nt].s, acc2[a][nt], 0, 0, 0);
  }

  // ---- LN2 stats ----
#pragma unroll
  for (int nt = 0; nt < 2; ++nt) {
    float s = 0.f, s2 = 0.f;
#pragma unroll
    for (int a = 0; a < 4; ++a)
#pragma unroll
      for (int r = 0; r < 4; ++r) { float v = acc2[a][nt][r]; s += v; s2 += v * v; }
    s += __shfl_xor(s, 16); s += __shfl_xor(s, 32);
    s2 += __shfl_xor(s2, 16); s2 += __shfl_xor(s2, 32);
    if (l < 16) { red2s[w][l + 16 * nt] = s; red2q[w][l + 16 * nt] = s2; }
  }
  __syncthreads();

  // ---- apply LN2 + sigmoid + gate-mul, float4 stores ----
  float* ob = out + (size_t)b * TT * DIMV + CC;
#pragma unroll
  for (int nt = 0; nt < 2; ++nt) {
    int c = (l & 15) + 16 * nt;
    int t = t0 + c;
    if (t < TT) {
      float S = red2s[0][c] + red2s[1][c] + red2s[2][c] + red2s[3][c];
      float S2 = red2q[0][c] + red2q[1][c] + red2q[2][c] + red2q[3][c];
      float mean = S * (1.f / 256.f);
      float var = S2 * (1.f / 256.f) - mean * mean;
      float rstd = rsqrtf(var + 1e-5f);
      int xrow = c + 2;
#pragma unroll
      for (int a = 0; a < 4; ++a) {
        int o0 = g * 128 + (half * 4 + a) * 16 + 4 * (l >> 4);
        float4 gg = *(const float4*)&g2[o0];
        float4 bb = *(const float4*)&b2[o0];
        float gv[4] = {gg.x, gg.y, gg.z, gg.w};
        float bv[4] = {bb.x, bb.y, bb.z, bb.w};
        uint2 xv2 = *(const uint2*)&xs[xrow * XSTD + (o0 >> 1)];
        float xvv[4] = { b2f((ushort_t)(xv2.x & 0xffff)), b2f((ushort_t)(xv2.x >> 16)),
                         b2f((ushort_t)(xv2.y & 0xffff)), b2f((ushort_t)(xv2.y >> 16)) };
        f32x4 res;
#pragma unroll
        for (int r = 0; r < 4; ++r) {
          float xn = (acc2[a][nt][r] - mean) * rstd * gv[r] + bv[r];
          res[r] = xvv[r] * sigmoid_f(xn);
        }
        *(f32x4*)&ob[(size_t)t * DIMV + o0] = res;
      }
    }
  }
}

// ---------------- launch ----------------

extern "C" void kernel_launch(void* const* d_in, const int* in_sizes, int n_in,
                              void* d_out, int out_size, void* d_ws, size_t ws_size,
                              hipStream_t stream) {
  const float* x  = (const float*)d_in[0];
  const float* lf = (const float*)d_in[1];
  const float* w1 = (const float*)d_in[2];
  const float* w2 = (const float*)d_in[3];
  const float* g1 = (const float*)d_in[4];
  const float* b1 = (const float*)d_in[5];
  const float* g2 = (const float*)d_in[6];
  const float* b2 = (const float*)d_in[7];
  float* out = (float*)d_out;

  char* ws = (char*)d_ws;
  float*    A     = (float*)(ws);                   // 237 KB
  ushort_t* Ffrag = (ushort_t*)(ws + 262144);       // 128 KB
  ushort_t* w1f   = (ushort_t*)(ws + 393216);       // 96 KB
  ushort_t* w2f   = (ushort_t*)(ws + 491520);       // 96 KB

  k_compute_A<<<FF, 256, 0, stream>>>(lf, A);
  k_compute_M<<<256, 256, 0, stream>>>(A, Ffrag);
  k_prep_w<<<384, 256, 0, stream>>>(w1, w2, w1f, w2f);
  k_res<<<BB * 4, 256, 0, stream>>>(x, Ffrag, out);
  k_gate<<<BB * NTIL, 256, 0, stream>>>(x, w1f, g1, b1, w2f, g2, b2, out);
}

// Round 6
// 211.545 us; speedup vs baseline: 29.5213x; 1.1101x over previous
//
#include <hip/hip_runtime.h>
#include <math.h>

typedef unsigned short ushort_t;
typedef unsigned int uint_t;
typedef __attribute__((ext_vector_type(8))) short short8v;   // 8 bf16 = 4 VGPR
typedef __attribute__((ext_vector_type(4))) float f32x4;

#define BB   512
#define TT   243
#define DIMV 512
#define CC   256
#define CHH  128
#define FF   122
#define NKK  122

__device__ __forceinline__ float b2f(ushort_t u) {
  union { uint_t i; float f; } z; z.i = ((uint_t)u) << 16; return z.f;
}
__device__ __forceinline__ ushort_t f2b(float f) {
  union { float f; uint_t i; } z; z.f = f;
  uint_t r = (z.i + 0x7fffu + ((z.i >> 16) & 1u)) >> 16;
  return (ushort_t)r;
}
// packed f32x2 -> bf16x2 in one VALU instr (RNE)
__device__ __forceinline__ uint_t pack2(float a, float b) {
  uint_t r;
  asm("v_cvt_pk_bf16_f32 %0, %1, %2" : "=v"(r) : "v"(a), "v"(b));
  return r;
}
// branchless gelu: A&S 7.1.26 erf, |eps|<=1.5e-7
__device__ __forceinline__ float gelu_f(float x) {
  float z = fabsf(x) * 0.70710678118654752f;
  float t = __builtin_amdgcn_rcpf(fmaf(0.3275911f, z, 1.0f));
  float p = fmaf(1.061405429f, t, -1.453152027f);
  p = fmaf(p, t, 1.421413741f);
  p = fmaf(p, t, -0.284496736f);
  p = fmaf(p, t, 0.254829592f);
  p = p * t;
  float e = __expf(-z * z);
  float erfa = 1.0f - p * e;
  float erfs = copysignf(erfa, x);
  return 0.5f * x * (1.0f + erfs);
}
__device__ __forceinline__ float sigmoid_f(float x) {
  return __builtin_amdgcn_rcpf(1.0f + __expf(-x));
}
union FragU { uint_t u[4]; short8v s; };

// ---------------- prep1: compute_A (blocks 0..121) + weight pack (blocks 122..505) ----------------

__global__ __launch_bounds__(256) void k_prep1(const float* __restrict__ lf, float* __restrict__ A,
    const float* __restrict__ w1, const float* __restrict__ w2,
    ushort_t* __restrict__ w1f, ushort_t* __restrict__ w2f) {
  __shared__ float2 tab[TT];
  int bid = blockIdx.x;
  if (bid < FF) {
    int f = bid;
    int tp = threadIdx.x;
    if (tp < TT) {
      float s, c;
      sincosf(6.28318530717958647692f * (float)tp / (float)TT, &s, &c);
      tab[tp] = make_float2(s, c);
    }
    __syncthreads();
    if (tp >= TT) return;
    float are = 0.f, aim = 0.f;
    int m = 0;
    const float* lrow = lf + (size_t)f * NKK * 2;
    for (int k = 0; k < NKK; ++k) {
      float2 sc = tab[m];
      float lr = lrow[2 * k], li = lrow[2 * k + 1];
      are = fmaf(lr, sc.y, fmaf(li, sc.x, are));
      aim = fmaf(li, sc.y, fmaf(-lr, sc.x, aim));
      m += tp; if (m >= TT) m -= TT;
    }
    A[(f * TT + tp) * 2 + 0] = are;
    A[(f * TT + tp) * 2 + 1] = aim;
  } else {
    int q = (bid - FF) * 256 + threadIdx.x;
    if (q < 49152) {
      int j = q & 7, l = (q >> 3) & 63, ot = (q >> 9) & 3, rest = q >> 11;
      int ks = rest % 12, g = rest / 12;
      int o = ot * 16 + (l & 15);
      int k = ks * 32 + 8 * (l >> 4) + j;
      int dk = k >> 7, i = k & 127;
      w1f[q] = f2b(w1[(g * 64 + o) * 384 + i * 3 + dk]);
    } else if (q < 98304) {
      int q2 = q - 49152;
      int j = q2 & 7, l = (q2 >> 3) & 63, ot = (q2 >> 9) & 7, rest = q2 >> 12;
      int ks = rest % 6, g = rest / 6;
      int o = ot * 16 + (l & 15);
      int k = ks * 32 + 8 * (l >> 4) + j;
      int dk = k >> 6, i = k & 63;
      w2f[q2] = f2b(w2[(g * 128 + o) * 192 + i * 3 + dk]);
    }
  }
}

// F[t][tp] (256x256 zero-padded) in MFMA fragment order:
// Ffrag[((kstep*16 + mt)*64 + lane)*8 + j] = F[mt*16 + lane%16][kstep*32 + (lane/16)*8 + j]
__global__ void k_compute_M(const float* __restrict__ A, ushort_t* __restrict__ Ffrag) {
  __shared__ float2 tab[TT];
  int t = blockIdx.x;            // 0..255
  int tp = threadIdx.x;          // 0..255
  if (tp < TT) {
    float s, c;
    sincosf(6.28318530717958647692f * (float)tp / (float)TT, &s, &c);
    tab[tp] = make_float2(s, c);
  }
  __syncthreads();
  float val = 0.f;
  if (t < TT && tp < TT) {
    float acc = A[tp * 2 + 0];
    int m = t;
    for (int f = 1; f < FF; ++f) {
      float2 sc = tab[m];
      float ar = A[(f * TT + tp) * 2 + 0];
      float ai = A[(f * TT + tp) * 2 + 1];
      acc = fmaf(2.f * ar, sc.y, fmaf(-2.f * ai, sc.x, acc));
      m += t; if (m >= TT) m -= TT;
    }
    val = acc * (1.0f / (float)TT);
  }
  int kstep = tp >> 5, ko = tp & 31, p = ko >> 3, j = ko & 7;
  int mt = t >> 4, row = t & 15, lane = p * 16 + row;
  Ffrag[(((kstep * 16 + mt) * 64) + lane) * 8 + j] = f2b(val);
}

// ---------------- fused main kernel: res blocks + gate blocks, interleaved 1:2 ----------------

#define RST   17    // res LDS row stride (dwords)
#define BT    32
#define NTIL  8     // ceil(243/32)
#define XROWS 36
#define XSTD  132   // dwords per xs row (256 bf16 + pad)
#define HROWS 34
#define HSTD  68    // dwords per hs row (128 bf16 + pad)
// smem dwords: gate = 36*132 + 34*68 + 2*4*48 + 2*4*32 = 7704 ; res = 2*64*17 = 2176
#define SMEM_DW 7704

__device__ __forceinline__ void res_path(int rid, uint_t* smem,
    const float* __restrict__ x, const ushort_t* __restrict__ Ffrag, float* __restrict__ out) {
  uint_t* xs = smem;                            // [2][64*RST]
  int b = rid >> 2, c0 = (rid & 3) * 64;
  int tid = threadIdx.x, l = tid & 63, w = tid >> 6;
  const float* xb = x + (size_t)b * TT * DIMV + c0;
  const short8v* Fp = (const short8v*)Ffrag;

  f32x4 acc[4][4];                              // [q = nt-local][m]
#pragma unroll
  for (int q = 0; q < 4; ++q)
#pragma unroll
    for (int m = 0; m < 4; ++m) acc[q][m] = (f32x4){0.f, 0.f, 0.f, 0.f};

  float v0[4], v1[4];
  int cc = tid & 63, kp0 = tid >> 6;

#pragma unroll
  for (int it = 0; it < 4; ++it) {
    int kp = kp0 + 4 * it, tp = 2 * kp;
    v0[it] = (tp < TT) ? xb[(size_t)tp * DIMV + cc] : 0.f;
    v1[it] = (tp + 1 < TT) ? xb[(size_t)(tp + 1) * DIMV + cc] : 0.f;
  }
#pragma unroll
  for (int it = 0; it < 4; ++it) xs[cc * RST + kp0 + 4 * it] = pack2(v0[it], v1[it]);
  __syncthreads();

  for (int ks = 0; ks < 8; ++ks) {
    int cur = ks & 1;
    if (ks < 7) {
#pragma unroll
      for (int it = 0; it < 4; ++it) {
        int kp = kp0 + 4 * it, tp = (ks + 1) * 32 + 2 * kp;
        v0[it] = (tp < TT) ? xb[(size_t)tp * DIMV + cc] : 0.f;
        v1[it] = (tp + 1 < TT) ? xb[(size_t)(tp + 1) * DIMV + cc] : 0.f;
      }
    }
    FragU bfr[4];
#pragma unroll
    for (int q = 0; q < 4; ++q) bfr[q].s = Fp[(ks * 16 + 4 * w + q) * 64 + l];
#pragma unroll
    for (int m = 0; m < 4; ++m) {
      FragU af;
      const uint_t* pp = &xs[cur * (64 * RST) + (16 * m + (l & 15)) * RST + 4 * (l >> 4)];
      af.u[0] = pp[0]; af.u[1] = pp[1]; af.u[2] = pp[2]; af.u[3] = pp[3];
#pragma unroll
      for (int q = 0; q < 4; ++q)
        acc[q][m] = __builtin_amdgcn_mfma_f32_16x16x32_bf16(af.s, bfr[q].s, acc[q][m], 0, 0, 0);
    }
    if (ks < 7) {
#pragma unroll
      for (int it = 0; it < 4; ++it)
        xs[(cur ^ 1) * (64 * RST) + cc * RST + kp0 + 4 * it] = pack2(v0[it], v1[it]);
    }
    __syncthreads();
  }

  float* ob = out + (size_t)b * TT * DIMV + c0;
#pragma unroll
  for (int q = 0; q < 4; ++q) {
    int t = (4 * w + q) * 16 + (l & 15);
    if (t < TT) {
#pragma unroll
      for (int m = 0; m < 4; ++m)
        *(f32x4*)&ob[(size_t)t * DIMV + 16 * m + 4 * (l >> 4)] = acc[q][m];
    }
  }
}

__device__ __forceinline__ void gate_path(int gid, uint_t* smem,
    const float* __restrict__ x,
    const ushort_t* __restrict__ w1f, const float* __restrict__ g1, const float* __restrict__ b1,
    const ushort_t* __restrict__ w2f, const float* __restrict__ g2, const float* __restrict__ b2,
    float* __restrict__ out) {
  uint_t* xs = smem;                            // [XROWS*XSTD]
  uint_t* hs = smem + XROWS * XSTD;             // [HROWS*HSTD]
  float* red1s = (float*)(hs + HROWS * HSTD);   // [4][48]
  float* red1q = red1s + 4 * 48;
  float* red2s = red1q + 4 * 48;                // [4][32]
  float* red2q = red2s + 4 * 32;
  int b = gid >> 3, t0 = (gid & 7) * BT;
  int tid = threadIdx.x, l = tid & 63, w = tid >> 6;
  int g = w >> 1, half = w & 1;

  // ---- stage x gate half, rows t0-2 .. t0+33, bf16, float4 loads ----
  const float* xb = x + (size_t)b * TT * DIMV + CC;
#pragma unroll 3
  for (int it = 0; it < 9; ++it) {
    int e = tid + it * 256;
    int r = e >> 6, cq = e & 63;
    int t = t0 - 2 + r;
    float4 v = make_float4(0.f, 0.f, 0.f, 0.f);
    if (t >= 0 && t < TT) v = *(const float4*)&xb[(size_t)t * DIMV + 4 * cq];
    *(uint2*)&xs[r * XSTD + 2 * cq] = make_uint2(pack2(v.x, v.y), pack2(v.z, v.w));
  }
  __syncthreads();

  // ---- conv1: M=128 o, N=48 cols (c=0..47; t_out = t0-1+c, valid c<34), K=384 ----
  const short8v* w1p = (const short8v*)w1f;
  int gdw = g * 64;
  f32x4 acc1[2][3];
#pragma unroll
  for (int a = 0; a < 2; ++a)
#pragma unroll
    for (int nt = 0; nt < 3; ++nt) acc1[a][nt] = (f32x4){0.f, 0.f, 0.f, 0.f};

  for (int ks = 0; ks < 12; ++ks) {
    short8v af[2];
#pragma unroll
    for (int a = 0; a < 2; ++a)
      af[a] = w1p[((g * 12 + ks) * 4 + half * 2 + a) * 64 + l];
    int dk = ks >> 2, i0dw = (ks & 3) * 16;
    FragU bf[3];
#pragma unroll
    for (int nt = 0; nt < 3; ++nt) {
      int row = (l & 15) + 16 * nt + dk;
      if (nt == 2) row = row > (XROWS - 1) ? (XROWS - 1) : row;
      const uint4* pp = (const uint4*)&xs[row * XSTD + gdw + i0dw + 4 * (l >> 4)];
      uint4 qv = *pp;
      bf[nt].u[0] = qv.x; bf[nt].u[1] = qv.y; bf[nt].u[2] = qv.z; bf[nt].u[3] = qv.w;
    }
#pragma unroll
    for (int a = 0; a < 2; ++a)
#pragma unroll
      for (int nt = 0; nt < 3; ++nt)
        acc1[a][nt] = __builtin_amdgcn_mfma_f32_16x16x32_bf16(af[a], bf[nt].s, acc1[a][nt], 0, 0, 0);
  }

  // ---- LN1 stats per col ----
#pragma unroll
  for (int nt = 0; nt < 3; ++nt) {
    float s = 0.f, s2 = 0.f;
#pragma unroll
    for (int a = 0; a < 2; ++a)
#pragma unroll
      for (int r = 0; r < 4; ++r) { float v = acc1[a][nt][r]; s += v; s2 += v * v; }
    s += __shfl_xor(s, 16); s += __shfl_xor(s, 32);
    s2 += __shfl_xor(s2, 16); s2 += __shfl_xor(s2, 32);
    if (l < 16) { red1s[w * 48 + l + 16 * nt] = s; red1q[w * 48 + l + 16 * nt] = s2; }
  }
  __syncthreads();

  // ---- apply LN1 + gelu, write h (bf16) to hs ----
#pragma unroll
  for (int nt = 0; nt < 3; ++nt) {
    int c = (l & 15) + 16 * nt;
    if (c < HROWS) {
      int t_out = t0 - 1 + c;
      bool valid = (t_out >= 0 && t_out < TT);
      float S = red1s[0 * 48 + c] + red1s[1 * 48 + c] + red1s[2 * 48 + c] + red1s[3 * 48 + c];
      float S2 = red1q[0 * 48 + c] + red1q[1 * 48 + c] + red1q[2 * 48 + c] + red1q[3 * 48 + c];
      float mean = S * (1.f / 128.f);
      float var = S2 * (1.f / 128.f) - mean * mean;
      float rstd = rsqrtf(var + 1e-5f);
#pragma unroll
      for (int a = 0; a < 2; ++a) {
        int o0 = g * 64 + half * 32 + a * 16 + 4 * (l >> 4);
        float4 gg = *(const float4*)&g1[o0];
        float4 bb = *(const float4*)&b1[o0];
        float gv[4] = {gg.x, gg.y, gg.z, gg.w};
        float bv[4] = {bb.x, bb.y, bb.z, bb.w};
        float h4[4];
#pragma unroll
        for (int r = 0; r < 4; ++r) {
          float xn = (acc1[a][nt][r] - mean) * rstd * gv[r] + bv[r];
          h4[r] = valid ? gelu_f(xn) : 0.f;
        }
        *(uint2*)&hs[c * HSTD + (o0 >> 1)] =
            make_uint2(pack2(h4[0], h4[1]), pack2(h4[2], h4[3]));
      }
    }
  }
  __syncthreads();

  // ---- conv2: M=256 o, N=32 t, K=192 ----
  const short8v* w2p = (const short8v*)w2f;
  int gdw2 = g * 32;
  f32x4 acc2[4][2];
#pragma unroll
  for (int a = 0; a < 4; ++a)
#pragma unroll
    for (int nt = 0; nt < 2; ++nt) acc2[a][nt] = (f32x4){0.f, 0.f, 0.f, 0.f};

  for (int ks = 0; ks < 6; ++ks) {
    short8v af[4];
#pragma unroll
    for (int a = 0; a < 4; ++a)
      af[a] = w2p[((g * 6 + ks) * 8 + half * 4 + a) * 64 + l];
    int dk = ks >> 1, i0dw = (ks & 1) * 16;
    FragU bf[2];
#pragma unroll
    for (int nt = 0; nt < 2; ++nt) {
      int row = (l & 15) + 16 * nt + dk;
      const uint4* pp = (const uint4*)&hs[row * HSTD + gdw2 + i0dw + 4 * (l >> 4)];
      uint4 qv = *pp;
      bf[nt].u[0] = qv.x; bf[nt].u[1] = qv.y; bf[nt].u[2] = qv.z; bf[nt].u[3] = qv.w;
    }
#pragma unroll
    for (int a = 0; a < 4; ++a)
#pragma unroll
      for (int nt = 0; nt < 2; ++nt)
        acc2[a][nt] = __builtin_amdgcn_mfma_f32_16x16x32_bf16(af[a], bf[nt].s, acc2[a][nt], 0, 0, 0);
  }

  // ---- LN2 stats ----
#pragma unroll
  for (int nt = 0; nt < 2; ++nt) {
    float s = 0.f, s2 = 0.f;
#pragma unroll
    for (int a = 0; a < 4; ++a)
#pragma unroll
      for (int r = 0; r < 4; ++r) { float v = acc2[a][nt][r]; s += v; s2 += v * v; }
    s += __shfl_xor(s, 16); s += __shfl_xor(s, 32);
    s2 += __shfl_xor(s2, 16); s2 += __shfl_xor(s2, 32);
    if (l < 16) { red2s[w * 32 + l + 16 * nt] = s; red2q[w * 32 + l + 16 * nt] = s2; }
  }
  __syncthreads();

  // ---- apply LN2 + sigmoid + gate-mul, float4 stores ----
  float* ob = out + (size_t)b * TT * DIMV + CC;
#pragma unroll
  for (int nt = 0; nt < 2; ++nt) {
    int c = (l & 15) + 16 * nt;
    int t = t0 + c;
    if (t < TT) {
      float S = red2s[0 * 32 + c] + red2s[1 * 32 + c] + red2s[2 * 32 + c] + red2s[3 * 32 + c];
      float S2 = red2q[0 * 32 + c] + red2q[1 * 32 + c] + red2q[2 * 32 + c] + red2q[3 * 32 + c];
      float mean = S * (1.f / 256.f);
      float var = S2 * (1.f / 256.f) - mean * mean;
      float rstd = rsqrtf(var + 1e-5f);
      int xrow = c + 2;
#pragma unroll
      for (int a = 0; a < 4; ++a) {
        int o0 = g * 128 + (half * 4 + a) * 16 + 4 * (l >> 4);
        float4 gg = *(const float4*)&g2[o0];
        float4 bb = *(const float4*)&b2[o0];
        float gv[4] = {gg.x, gg.y, gg.z, gg.w};
        float bv[4] = {bb.x, bb.y, bb.z, bb.w};
        uint2 xv2 = *(const uint2*)&xs[xrow * XSTD + (o0 >> 1)];
        float xvv[4] = { b2f((ushort_t)(xv2.x & 0xffff)), b2f((ushort_t)(xv2.x >> 16)),
                         b2f((ushort_t)(xv2.y & 0xffff)), b2f((ushort_t)(xv2.y >> 16)) };
        f32x4 res;
#pragma unroll
        for (int r = 0; r < 4; ++r) {
          float xn = (acc2[a][nt][r] - mean) * rstd * gv[r] + bv[r];
          res[r] = xvv[r] * sigmoid_f(xn);
        }
        *(f32x4*)&ob[(size_t)t * DIMV + o0] = res;
      }
    }
  }
}

__global__ __launch_bounds__(256, 4) void k_main(const float* __restrict__ x,
    const ushort_t* __restrict__ Ffrag,
    const ushort_t* __restrict__ w1f, const float* __restrict__ g1, const float* __restrict__ b1,
    const ushort_t* __restrict__ w2f, const float* __restrict__ g2, const float* __restrict__ b2,
    float* __restrict__ out) {
  __shared__ uint_t smem[SMEM_DW];
  int bid = blockIdx.x;
  int k = bid / 3, r = bid - 3 * k;
  if (r == 0) {
    res_path(k, smem, x, Ffrag, out);
  } else {
    gate_path(2 * k + (r - 1), smem, x, w1f, g1, b1, w2f, g2, b2, out);
  }
}

// ---------------- launch ----------------

extern "C" void kernel_launch(void* const* d_in, const int* in_sizes, int n_in,
                              void* d_out, int out_size, void* d_ws, size_t ws_size,
                              hipStream_t stream) {
  const float* x  = (const float*)d_in[0];
  const float* lf = (const float*)d_in[1];
  const float* w1 = (const float*)d_in[2];
  const float* w2 = (const float*)d_in[3];
  const float* g1 = (const float*)d_in[4];
  const float* b1 = (const float*)d_in[5];
  const float* g2 = (const float*)d_in[6];
  const float* b2 = (const float*)d_in[7];
  float* out = (float*)d_out;

  char* ws = (char*)d_ws;
  float*    A     = (float*)(ws);                   // 237 KB
  ushort_t* Ffrag = (ushort_t*)(ws + 262144);       // 128 KB
  ushort_t* w1f   = (ushort_t*)(ws + 393216);       // 96 KB
  ushort_t* w2f   = (ushort_t*)(ws + 491520);       // 96 KB

  k_prep1<<<FF + 384, 256, 0, stream>>>(lf, A, w1, w2, w1f, w2f);
  k_compute_M<<<256, 256, 0, stream>>>(A, Ffrag);
  k_main<<<BB * 4 * 3, 256, 0, stream>>>(x, Ffrag, w1f, g1, b1, w2f, g2, b2, out);
}